// Round 3
// baseline (17348.013 us; speedup 1.0000x reference)
//
#include <hip/hip_runtime.h>

static inline int cdiv(int a, int b) { return (a + b - 1) / b; }

#define TM 128
#define TN 128
#define GBK 16

// ---------------------------------------------------------------------------
// GEMM: C[m,n] = alpha * sum_k opA(A)[m,k]*opB(B)[k,n] + (Add?Add[m,n]:0) + (addI&&m==n?1:0)
// OPA==0: A is MxK row-major.  OPA==1: A physical KxM; opA[m,k]=A[k*lda+m]
// OPB==0: B is KxN row-major.  OPB==1: B physical NxK; opB[k,n]=B[n*ldb+k]
// REQUIRES: M,N multiples of 128; K multiple of 16; 16B-aligned pointers.
// ---------------------------------------------------------------------------
template<int OPA, int OPB>
__global__ __launch_bounds__(256)
void gemm_kernel(int M, int N, int K,
                 const float* __restrict__ A, int lda,
                 const float* __restrict__ B, int ldb,
                 float* __restrict__ C, int ldc,
                 float alpha,
                 const float* __restrict__ Add, int ldadd, int addI)
{
  __shared__ float As[GBK][TM];
  __shared__ float Bs[GBK][TN];
  const int tid = (int)threadIdx.x;
  const int tx = tid & 15;
  const int ty = tid >> 4;
  const int bm = (int)blockIdx.y * TM;
  const int bn = (int)blockIdx.x * TN;

  float acc[8][8];
#pragma unroll
  for (int i = 0; i < 8; ++i)
#pragma unroll
    for (int j = 0; j < 8; ++j) acc[i][j] = 0.f;

  for (int k0 = 0; k0 < K; k0 += GBK) {
    if (OPA == 0) {
#pragma unroll
      for (int l = 0; l < 2; ++l) {
        int flat = tid + 256 * l;
        int row = flat >> 2, c = flat & 3;
        const float4 v = *reinterpret_cast<const float4*>(&A[(size_t)(bm + row) * lda + k0 + c * 4]);
        As[c * 4 + 0][row] = v.x; As[c * 4 + 1][row] = v.y;
        As[c * 4 + 2][row] = v.z; As[c * 4 + 3][row] = v.w;
      }
    } else {
#pragma unroll
      for (int l = 0; l < 2; ++l) {
        int flat = tid + 256 * l;
        int kk = flat >> 5, mc = flat & 31;
        const float4 v = *reinterpret_cast<const float4*>(&A[(size_t)(k0 + kk) * lda + bm + mc * 4]);
        *reinterpret_cast<float4*>(&As[kk][mc * 4]) = v;
      }
    }
    if (OPB == 0) {
#pragma unroll
      for (int l = 0; l < 2; ++l) {
        int flat = tid + 256 * l;
        int kk = flat >> 5, nc = flat & 31;
        const float4 v = *reinterpret_cast<const float4*>(&B[(size_t)(k0 + kk) * ldb + bn + nc * 4]);
        *reinterpret_cast<float4*>(&Bs[kk][nc * 4]) = v;
      }
    } else {
#pragma unroll
      for (int l = 0; l < 2; ++l) {
        int flat = tid + 256 * l;
        int row = flat >> 2, c = flat & 3;
        const float4 v = *reinterpret_cast<const float4*>(&B[(size_t)(bn + row) * ldb + k0 + c * 4]);
        Bs[c * 4 + 0][row] = v.x; Bs[c * 4 + 1][row] = v.y;
        Bs[c * 4 + 2][row] = v.z; Bs[c * 4 + 3][row] = v.w;
      }
    }
    __syncthreads();
#pragma unroll
    for (int kk = 0; kk < GBK; ++kk) {
      float a[8], b[8];
      *reinterpret_cast<float4*>(&a[0]) = *reinterpret_cast<const float4*>(&As[kk][ty * 4]);
      *reinterpret_cast<float4*>(&a[4]) = *reinterpret_cast<const float4*>(&As[kk][64 + ty * 4]);
      *reinterpret_cast<float4*>(&b[0]) = *reinterpret_cast<const float4*>(&Bs[kk][tx * 4]);
      *reinterpret_cast<float4*>(&b[4]) = *reinterpret_cast<const float4*>(&Bs[kk][64 + tx * 4]);
#pragma unroll
      for (int i = 0; i < 8; ++i)
#pragma unroll
        for (int j = 0; j < 8; ++j)
          acc[i][j] = fmaf(a[i], b[j], acc[i][j]);
    }
    __syncthreads();
  }
#pragma unroll
  for (int i = 0; i < 8; ++i) {
    int gm = bm + ((i < 4) ? (ty * 4 + i) : (64 + ty * 4 + i - 4));
#pragma unroll
    for (int jh = 0; jh < 2; ++jh) {
      int gn0 = bn + (jh ? (64 + tx * 4) : (tx * 4));
      float vv[4];
#pragma unroll
      for (int j = 0; j < 4; ++j) vv[j] = alpha * acc[i][jh * 4 + j];
      if (Add) {
        const float4 ad = *reinterpret_cast<const float4*>(&Add[(size_t)gm * ldadd + gn0]);
        vv[0] += ad.x; vv[1] += ad.y; vv[2] += ad.z; vv[3] += ad.w;
      }
      if (addI) {
#pragma unroll
        for (int j = 0; j < 4; ++j) if (gm == gn0 + j) vv[j] += 1.f;
      }
      float4 v; v.x = vv[0]; v.y = vv[1]; v.z = vv[2]; v.w = vv[3];
      *reinterpret_cast<float4*>(&C[(size_t)gm * ldc + gn0]) = v;
    }
  }
  (void)M; (void)N;
}

static void gemm(hipStream_t st, int opa, int opb, int M, int N, int K,
                 const float* A, int lda, const float* B, int ldb,
                 float* C, int ldc, float alpha,
                 const float* Add, int ldadd, int addI)
{
  dim3 grid(cdiv(N, TN), cdiv(M, TM)), blk(256);
  if (opa == 0 && opb == 0)
    gemm_kernel<0,0><<<grid, blk, 0, st>>>(M, N, K, A, lda, B, ldb, C, ldc, alpha, Add, ldadd, addI);
  else if (opa == 0 && opb == 1)
    gemm_kernel<0,1><<<grid, blk, 0, st>>>(M, N, K, A, lda, B, ldb, C, ldc, alpha, Add, ldadd, addI);
  else
    gemm_kernel<1,0><<<grid, blk, 0, st>>>(M, N, K, A, lda, B, ldb, C, ldc, alpha, Add, ldadd, addI);
}

// ---------------------------------------------------------------------------
// Matvec helpers
// ---------------------------------------------------------------------------
__global__ __launch_bounds__(256)
void mv_n_kernel(int M, int K, const float* A, int lda, const float* x, float* y)
{
  int m = (int)blockIdx.x;
  if (m >= M) return;
  const float* row = A + (size_t)m * lda;
  float s = 0.f;
  for (int k = (int)threadIdx.x; k < K; k += 256) s += row[k] * x[k];
  __shared__ float red[256];
  red[threadIdx.x] = s;
  __syncthreads();
  for (int off = 128; off > 0; off >>= 1) {
    if ((int)threadIdx.x < off) red[threadIdx.x] += red[threadIdx.x + off];
    __syncthreads();
  }
  if (threadIdx.x == 0) y[m] = red[0];
}

__global__ __launch_bounds__(256)
void mv_t_kernel(int Nrows, int Ncols, const float* A, int lda,
                 const float* x, const float* addv, float* w)
{
  int e = (int)(blockIdx.x * blockDim.x + threadIdx.x);
  if (e >= Ncols) return;
  float s = 0.f;
  for (int n = 0; n < Nrows; ++n) s += A[(size_t)n * lda + e] * x[n];
  if (addv) s += addv[e];
  w[e] = s;
}

// ---------------------------------------------------------------------------
// elementwise helpers
// ---------------------------------------------------------------------------
__global__ __launch_bounds__(256)
void scale_cols_kernel(long long total, int E, const float* B, const float* sv, float* out)
{
  long long i = (long long)blockIdx.x * blockDim.x + threadIdx.x;
  if (i < total) {
    int e = (int)(i % E);
    out[i] = B[i] * sv[e];
  }
}

__global__ __launch_bounds__(256)
void build_h_kernel(long long total, int E,
                    const float* B, const float* LB, const float* L2B,
                    const float* w0, const float* w1, const float* w2,
                    const float* a, float* H)
{
  long long i = (long long)blockIdx.x * blockDim.x + threadIdx.x;
  if (i < total) {
    int e = (int)(i % E);
    float a1 = a[1], a2 = a[2], a3 = a[3];
    float b = B[i], lb = LB[i], l2b = L2B[i];
    H[i] = w0[e] * (a1 * b + a2 * lb + a3 * l2b)
         + w1[e] * (a2 * b + a3 * lb)
         + w2[e] * (a3 * b);
  }
}

__global__ __launch_bounds__(256)
void poly_resid_kernel(int Nn, const float* a, const float* q,
                       const float* c1, const float* c2, const float* c3,
                       const float* y, float* resid)
{
  int n = (int)(blockIdx.x * blockDim.x + threadIdx.x);
  if (n < Nn)
    resid[n] = y[n] - (a[0] * q[n] + a[1] * c1[n] + a[2] * c2[n] + a[3] * c3[n]);
}

__global__ __launch_bounds__(256)
void fzero_kernel(float* p, long long n)
{
  long long i = (long long)blockIdx.x * blockDim.x + threadIdx.x;
  if (i < n) p[i] = 0.f;
}

// ---------------------------------------------------------------------------
// index handling
// ---------------------------------------------------------------------------
__global__ __launch_bounds__(256)
void conv_idx_kernel(const void* src, int n, int* dst)
{
  const unsigned* u = (const unsigned*)src;
  bool is64 = (u[1] | u[3] | u[5] | u[7]) == 0u;
  int i = (int)(blockIdx.x * blockDim.x + threadIdx.x);
  if (i < n) dst[i] = is64 ? (int)((const long long*)src)[i] : ((const int*)src)[i];
}

__global__ __launch_bounds__(256)
void fill_int_kernel(int* p, int n, int v)
{
  int i = (int)(blockIdx.x * blockDim.x + threadIdx.x);
  if (i < n) p[i] = v;
}

__global__ __launch_bounds__(256)
void scatter_inv_kernel(const int* conn, int K, int* inv)
{
  int i = (int)(blockIdx.x * blockDim.x + threadIdx.x);
  if (i < K) inv[conn[i]] = i;
}

__global__ __launch_bounds__(256)
void mask_s_kernel(int E, const float* s_upd, const int* inv, float* s2, float* outS)
{
  int e = (int)(blockIdx.x * blockDim.x + threadIdx.x);
  if (e < E) {
    float v = (inv[e] >= 0) ? s_upd[e] : 0.f;
    s2[e] = v;
    outS[e] = v;
  }
}

__global__ __launch_bounds__(256)
void gather_cols_kernel(int Nr, int Kc, int E, const float* src, const int* conn, float* dst)
{
  long long i = (long long)blockIdx.x * blockDim.x + threadIdx.x;
  if (i < (long long)Nr * Kc) {
    int n = (int)(i / Kc), c = (int)(i % Kc);
    dst[i] = src[(size_t)n * E + conn[c]];
  }
}

__global__ __launch_bounds__(256)
void gather_scc_kernel(int Kc, int E, const float* Sig, const int* conn, float* Scc)
{
  long long i = (long long)blockIdx.x * blockDim.x + threadIdx.x;
  if (i < (long long)Kc * Kc) {
    int r = (int)(i / Kc), c = (int)(i % Kc);
    Scc[i] = Sig[(size_t)conn[r] * E + conn[c]];
  }
}

__global__ __launch_bounds__(256)
void write_sigma_out_kernel(long long total, int E, const float* Small, int Kc,
                            const int* inv, float* out)
{
  long long i = (long long)blockIdx.x * blockDim.x + threadIdx.x;
  if (i < total) {
    int r = (int)(i / E), c = (int)(i % E);
    int ir = inv[r], ic = inv[c];
    out[i] = (ir >= 0 && ic >= 0) ? Small[(size_t)ir * Kc + ic] : 0.f;
  }
}

// ---------------------------------------------------------------------------
// Cholesky leaf: factor 128x128 diag block in place (lower), right-looking,
// cooperative trailing update (256 threads: 8 row-groups x 32 lanes).
// ---------------------------------------------------------------------------
__global__ __launch_bounds__(256)
void chol_diag_kernel(float* A, int lda, int off)
{
  __shared__ float T[128][129];
  const int tid = (int)threadIdx.x;
  const int g = tid >> 5;       // row group 0..7
  const int lane = tid & 31;
  float* Ab = A + (size_t)off * lda + off;
  for (int idx = tid; idx < 128 * 128; idx += 256) {
    int rr = idx >> 7, cc = idx & 127;
    T[rr][cc] = Ab[(size_t)rr * lda + cc];
  }
  __syncthreads();
  for (int j = 0; j < 128; ++j) {
    float tjj = T[j][j];
    __syncthreads();
    float d = sqrtf(tjj);
    if (tid < 128 && tid >= j) T[tid][j] = (tid == j) ? d : T[tid][j] * (1.f / d);
    __syncthreads();
    // trailing: T[r][c] -= T[r][j]*T[c][j], j < c <= r < 128
    for (int r = j + 1 + g; r < 128; r += 8) {
      float ljr = T[r][j];
      for (int c = j + 1 + lane; c <= r; c += 32)
        T[r][c] -= ljr * T[c][j];
    }
    __syncthreads();
  }
  for (int idx = tid; idx < 128 * 128; idx += 256) {
    int rr = idx >> 7, cc = idx & 127;
    Ab[(size_t)rr * lda + cc] = T[rr][cc];
  }
}

// Panel TRSM: P := P * L11^{-T}. One thread per row, right-looking, ZERO
// barriers (rows independent); L11 read via wave-uniform (scalar) loads.
__global__ __launch_bounds__(128)
void chol_trsm_kernel(float* A, int lda, int off)
{
  __shared__ float rw[128][129];   // rw[elem][local_row]
  const int tid = (int)threadIdx.x;
  const float* Ld = A + (size_t)off * lda + off;
  float* Pb = A + (size_t)(off + 128 + (size_t)blockIdx.x * 128) * lda + off;
  // coalesced transposed load: iter t0 = local row, lanes = elements
  for (int t0 = 0; t0 < 128; ++t0)
    rw[tid][t0] = Pb[(size_t)t0 * lda + tid];
  __syncthreads();
  for (int j = 0; j < 128; ++j) {
    float w = rw[j][tid] / Ld[(size_t)j * lda + j];
    rw[j][tid] = w;
    for (int i = j + 1; i < 128; ++i)
      rw[i][tid] -= Ld[(size_t)i * lda + j] * w;
  }
  __syncthreads();
  for (int t0 = 0; t0 < 128; ++t0)
    Pb[(size_t)t0 * lda + tid] = rw[tid][t0];
}

static void cholesky(hipStream_t st, float* S, int n)
{
  const int nb = 128;
  for (int off = 0; off < n; off += nb) {
    chol_diag_kernel<<<1, 256, 0, st>>>(S, n, off);
    int mrem = n - off - nb;
    if (mrem > 0) {
      chol_trsm_kernel<<<mrem / 128, 128, 0, st>>>(S, n, off);
      float* P = S + (size_t)(off + nb) * n + off;
      float* Ct = S + (size_t)(off + nb) * n + (off + nb);
      gemm(st, 0, 1, mrem, mrem, nb, P, n, P, n, Ct, n, -1.f, Ct, n, 0);
    }
  }
}

// ---------------------------------------------------------------------------
// TRTRI of all 128x128 diag blocks, batched (block b -> diag block b).
// One thread per COLUMN of the inverse, right-looking, ZERO barriers.
// L read via wave-uniform (scalar) loads.
// ---------------------------------------------------------------------------
__global__ __launch_bounds__(128)
void trtri_diag_kernel(const float* L, int lda, float* Out, int ldo)
{
  __shared__ float X[128][129];    // X[row][col]
  const int c = (int)threadIdx.x;
  const int off = (int)blockIdx.x * 128;
  const float* Lb = L + (size_t)off * lda + off;
  for (int i = 0; i < 128; ++i) X[i][c] = (i == c) ? 1.f : 0.f;
  for (int j = 0; j < 128; ++j) {
    float invd = 1.f / Lb[(size_t)j * lda + j];
    float xj = X[j][c] * invd;     // 0 for c > j  -> no-op updates (uniform)
    X[j][c] = xj;
    for (int i = j + 1; i < 128; ++i)
      X[i][c] -= Lb[(size_t)i * lda + j] * xj;
  }
  float* Ob = Out + (size_t)off * ldo + off;
  for (int i = 0; i < 128; ++i)
    Ob[(size_t)i * ldo + c] = X[i][c];
}

// Build Sinv = L^{-T} L^{-1} from the Cholesky factor (Lf, lower, in S buffer).
// Linv: n*n scratch. TT: >= 512*512 scratch.
static void make_sinv(hipStream_t st, const float* Lf, float* Linv, float* Sinv, float* TT, int n)
{
  long long nn = (long long)n * n;
  fzero_kernel<<<cdiv((int)nn, 256), 256, 0, st>>>(Linv, nn);
  trtri_diag_kernel<<<n / 128, 128, 0, st>>>(Lf, n, Linv, n);
  for (int m = 128; m < n; m <<= 1) {
    for (int o = 0; o + 2 * m <= n; o += 2 * m) {
      gemm(st, 0, 0, m, m, m, Lf + (size_t)(o + m) * n + o, n,
           Linv + (size_t)o * n + o, n, TT, m, 1.f, nullptr, 0, 0);
      gemm(st, 0, 0, m, m, m, Linv + (size_t)(o + m) * n + (o + m), n,
           TT, m, Linv + (size_t)(o + m) * n + o, n, -1.f, nullptr, 0, 0);
    }
  }
  gemm(st, 1, 0, n, n, n, Linv, n, Linv, n, Sinv, n, 1.f, nullptr, 0, 0);
}

// ---------------------------------------------------------------------------
extern "C" void kernel_launch(void* const* d_in, const int* in_sizes, int n_in,
                              void* d_out, int out_size, void* d_ws, size_t ws_size,
                              hipStream_t stream)
{
  const float* F  = (const float*)d_in[0];
  const float* B  = (const float*)d_in[1];
  const float* V  = (const float*)d_in[2];
  const float* W  = (const float*)d_in[3];
  const float* Sg = (const float*)d_in[4];
  const float* sv = (const float*)d_in[5];
  const float* av = (const float*)d_in[6];
  const float* q  = (const float*)d_in[7];
  const float* y  = (const float*)d_in[8];
  const void*  connRaw = d_in[10];

  const int E  = in_sizes[5];
  const int Nn = in_sizes[7];
  const int Kc = in_sizes[10];

  const size_t EE = (size_t)E * E;
  const size_t NE = (size_t)Nn * E;
  const size_t NN = (size_t)Nn * Nn;
  const size_t NK = (size_t)Nn * Kc;
  const size_t KK = (size_t)Kc * Kc;

  float* ws = (float*)d_ws;
  float* EE_A = ws;
  float* EE_B = EE_A + EE;
  float* NE_1 = EE_B + EE;
  float* NE_2 = NE_1 + NE;   // also Y / TT / T10 (time-disjoint)
  float* NE_3 = NE_2 + NE;
  float* NN_1 = NE_3 + NE;   // L / S factor
  float* NN_2 = NN_1 + NN;   // Linv
  float* NN_3 = NN_2 + NN;   // Sinv
  float* vec  = NN_3 + NN;
  float* s1    = vec;            vec += E;
  float* c1    = vec;            vec += Nn;
  float* c2    = vec;            vec += Nn;
  float* c3    = vec;            vec += Nn;
  float* w0    = vec;            vec += E;
  float* w1    = vec;            vec += E;
  float* w2    = vec;            vec += E;
  float* resid = vec;            vec += Nn;
  float* s_upd = vec;            vec += E;
  float* s2    = vec;            vec += E;
  int* conn32  = (int*)vec;
  int* invc    = conn32 + Kc;

  float* outS   = (float*)d_out;   // E
  float* outSig = outS + E;        // E*E; scratch until final write
  float* EE_C   = outSig;
  float* TT     = NE_2;            // trtri temp (used before Y/T10 live)

  const long long totNE = (long long)Nn * E;
  const long long totEE = (long long)E * E;

  // ---- stage 1 ----
  mv_n_kernel<<<E, 256, 0, stream>>>(E, E, F, E, sv, s1);                        // s1 = F s
  gemm(stream, 0, 0, E, E, E, F, E, Sg, E, EE_A, E, 1.f, nullptr, 0, 0);         // G1 = F Sigma
  gemm(stream, 0, 1, E, E, E, EE_A, E, F, E, EE_B, E, 1.f, V, E, 0);             // Sigma1 = G1 F^T + V
  scale_cols_kernel<<<cdiv((int)totNE, 256), 256, 0, stream>>>(totNE, E, B, s1, NE_1); // Bs
  gemm(stream, 0, 1, Nn, Nn, E, NE_1, E, B, E, NN_1, Nn, 1.f, nullptr, 0, 0);    // L = Bs B^T
  mv_n_kernel<<<Nn, 256, 0, stream>>>(Nn, Nn, NN_1, Nn, q, c1);
  mv_n_kernel<<<Nn, 256, 0, stream>>>(Nn, Nn, NN_1, Nn, c1, c2);
  mv_n_kernel<<<Nn, 256, 0, stream>>>(Nn, Nn, NN_1, Nn, c2, c3);
  mv_t_kernel<<<cdiv(E, 256), 256, 0, stream>>>(Nn, E, B, E, q,  nullptr, w0);
  mv_t_kernel<<<cdiv(E, 256), 256, 0, stream>>>(Nn, E, B, E, c1, nullptr, w1);
  mv_t_kernel<<<cdiv(E, 256), 256, 0, stream>>>(Nn, E, B, E, c2, nullptr, w2);
  poly_resid_kernel<<<cdiv(Nn, 256), 256, 0, stream>>>(Nn, av, q, c1, c2, c3, y, resid);
  gemm(stream, 0, 0, Nn, E, Nn, NN_1, Nn, B, E, NE_1, E, 1.f, nullptr, 0, 0);    // LB
  gemm(stream, 0, 0, Nn, E, Nn, NN_1, Nn, NE_1, E, NE_2, E, 1.f, nullptr, 0, 0); // L2B
  build_h_kernel<<<cdiv((int)totNE, 256), 256, 0, stream>>>(totNE, E, B, NE_1, NE_2, w0, w1, w2, av, NE_3); // H
  gemm(stream, 0, 0, Nn, E, E, NE_3, E, EE_B, E, NE_1, E, 1.f, nullptr, 0, 0);   // T2 = H Sigma1
  gemm(stream, 0, 1, Nn, Nn, E, NE_1, E, NE_3, E, NN_1, Nn, 1.f, W, Nn, 0);      // S = T2 H^T + W
  cholesky(stream, NN_1, Nn);
  make_sinv(stream, NN_1, NN_2, NN_3, TT, Nn);                                   // Sinv
  gemm(stream, 0, 0, Nn, E, Nn, NN_3, Nn, NE_1, E, NE_2, E, 1.f, nullptr, 0, 0); // Y = Sinv T2
  mv_t_kernel<<<cdiv(E, 256), 256, 0, stream>>>(Nn, E, NE_2, E, resid, s1, s_upd); // s_upd = s1 + Y^T resid
  gemm(stream, 1, 0, E, E, Nn, NE_2, E, NE_3, E, EE_A, E, -1.f, nullptr, 0, 1);  // ImKH = I - Y^T H
  gemm(stream, 0, 0, E, E, E, EE_A, E, EE_B, E, EE_C, E, 1.f, nullptr, 0, 0);    // T3 = ImKH Sigma1
  gemm(stream, 0, 1, E, E, E, EE_C, E, EE_A, E, EE_B, E, 1.f, nullptr, 0, 0);    // T4 = T3 ImKH^T
  gemm(stream, 1, 0, E, Nn, Nn, NE_2, E, W, Nn, NE_1, Nn, 1.f, nullptr, 0, 0);   // T5 = Y^T W
  gemm(stream, 0, 0, E, E, Nn, NE_1, Nn, NE_2, E, EE_B, E, 1.f, EE_B, E, 0);     // Sigma2 = T5 Y + T4

  // ---- masking / stage 2 ----
  conv_idx_kernel<<<cdiv(Kc, 256), 256, 0, stream>>>(connRaw, Kc, conn32);
  fill_int_kernel<<<cdiv(E, 256), 256, 0, stream>>>(invc, E, -1);
  scatter_inv_kernel<<<cdiv(Kc, 256), 256, 0, stream>>>(conn32, Kc, invc);
  mask_s_kernel<<<cdiv(E, 256), 256, 0, stream>>>(E, s_upd, invc, s2, outS);

  scale_cols_kernel<<<cdiv((int)totNE, 256), 256, 0, stream>>>(totNE, E, B, s2, NE_1); // Bs2
  gemm(stream, 0, 1, Nn, Nn, E, NE_1, E, B, E, NN_1, Nn, 1.f, nullptr, 0, 0);    // L2
  mv_n_kernel<<<Nn, 256, 0, stream>>>(Nn, Nn, NN_1, Nn, q, c1);
  mv_n_kernel<<<Nn, 256, 0, stream>>>(Nn, Nn, NN_1, Nn, c1, c2);
  mv_t_kernel<<<cdiv(E, 256), 256, 0, stream>>>(Nn, E, B, E, q,  nullptr, w0);
  mv_t_kernel<<<cdiv(E, 256), 256, 0, stream>>>(Nn, E, B, E, c1, nullptr, w1);
  mv_t_kernel<<<cdiv(E, 256), 256, 0, stream>>>(Nn, E, B, E, c2, nullptr, w2);
  gemm(stream, 0, 0, Nn, E, Nn, NN_1, Nn, B, E, NE_1, E, 1.f, nullptr, 0, 0);    // L2 B
  gemm(stream, 0, 0, Nn, E, Nn, NN_1, Nn, NE_1, E, NE_2, E, 1.f, nullptr, 0, 0); // L2^2 B
  build_h_kernel<<<cdiv((int)totNE, 256), 256, 0, stream>>>(totNE, E, B, NE_1, NE_2, w0, w1, w2, av, NE_3); // H2full
  gather_cols_kernel<<<cdiv((int)NK, 256), 256, 0, stream>>>(Nn, Kc, E, NE_3, conn32, EE_A);        // H2 (Nn x Kc)
  gather_scc_kernel<<<cdiv((int)KK, 256), 256, 0, stream>>>(Kc, E, EE_B, conn32, EE_A + NK);        // Scc (Kc x Kc)
  gemm(stream, 0, 0, Nn, Kc, Kc, EE_A, Kc, EE_A + NK, Kc, EE_B, Kc, 1.f, nullptr, 0, 0); // T7 = H2 Scc
  gemm(stream, 0, 1, Nn, Nn, Kc, EE_B, Kc, EE_A, Kc, NN_1, Nn, 1.f, W, Nn, 0);   // S2 = T7 H2^T + W
  cholesky(stream, NN_1, Nn);
  make_sinv(stream, NN_1, NN_2, NN_3, TT, Nn);
  gemm(stream, 0, 0, Nn, Kc, Nn, NN_3, Nn, EE_B, Kc, NE_1, Kc, 1.f, nullptr, 0, 0);  // Y2 = Sinv2 T7
  gemm(stream, 1, 0, Kc, Kc, Nn, NE_1, Kc, EE_A, Kc, EE_C, Kc, -1.f, nullptr, 0, 1); // ImKH2 = I - Y2^T H2
  gemm(stream, 0, 0, Kc, Kc, Kc, EE_C, Kc, EE_A + NK, Kc, EE_C + KK, Kc, 1.f, nullptr, 0, 0); // T8 = ImKH2 Scc
  gemm(stream, 0, 1, Kc, Kc, Kc, EE_C + KK, Kc, EE_C, Kc, EE_A + NK, Kc, 1.f, nullptr, 0, 0); // T9 = T8 ImKH2^T
  gemm(stream, 1, 0, Kc, Nn, Nn, NE_1, Kc, W, Nn, NE_2, Nn, 1.f, nullptr, 0, 0); // T10 = Y2^T W
  gemm(stream, 0, 0, Kc, Kc, Nn, NE_2, Nn, NE_1, Kc, EE_A + NK, Kc, 1.f, EE_A + NK, Kc, 0); // Small = T10 Y2 + T9

  write_sigma_out_kernel<<<cdiv((int)totEE, 256), 256, 0, stream>>>(totEE, E, EE_A + NK, Kc, invc, outSig);

  (void)n_in; (void)out_size; (void)ws_size;
}

// Round 4
// 8404.020 us; speedup vs baseline: 2.0643x; 2.0643x over previous
//
#include <hip/hip_runtime.h>

static inline int cdiv(int a, int b) { return (a + b - 1) / b; }

#define TM 128
#define TN 128
#define GBK 16

// ---------------------------------------------------------------------------
// GEMM: C[m,n] = alpha * sum_k opA(A)[m,k]*opB(B)[k,n] + (Add?Add[m,n]:0) + (addI&&m==n?1:0)
// OPA==0: A is MxK row-major.  OPA==1: A physical KxM; opA[m,k]=A[k*lda+m]
// OPB==0: B is KxN row-major.  OPB==1: B physical NxK; opB[k,n]=B[n*ldb+k]
// Batched over blockIdx.z via element strides zsA/zsB/zsC.
// REQUIRES: M,N multiples of 128; K multiple of 16; 16B-aligned pointers.
// ---------------------------------------------------------------------------
template<int OPA, int OPB>
__global__ __launch_bounds__(256)
void gemm_kernel(int M, int N, int K,
                 const float* __restrict__ A, int lda,
                 const float* __restrict__ B, int ldb,
                 float* __restrict__ C, int ldc,
                 float alpha,
                 const float* __restrict__ Add, int ldadd, int addI,
                 size_t zsA, size_t zsB, size_t zsC)
{
  A += (size_t)blockIdx.z * zsA;
  B += (size_t)blockIdx.z * zsB;
  C += (size_t)blockIdx.z * zsC;
  __shared__ float As[GBK][TM];
  __shared__ float Bs[GBK][TN];
  const int tid = (int)threadIdx.x;
  const int tx = tid & 15;
  const int ty = tid >> 4;
  const int bm = (int)blockIdx.y * TM;
  const int bn = (int)blockIdx.x * TN;

  float acc[8][8];
#pragma unroll
  for (int i = 0; i < 8; ++i)
#pragma unroll
    for (int j = 0; j < 8; ++j) acc[i][j] = 0.f;

  for (int k0 = 0; k0 < K; k0 += GBK) {
    if (OPA == 0) {
#pragma unroll
      for (int l = 0; l < 2; ++l) {
        int flat = tid + 256 * l;
        int row = flat >> 2, c = flat & 3;
        const float4 v = *reinterpret_cast<const float4*>(&A[(size_t)(bm + row) * lda + k0 + c * 4]);
        As[c * 4 + 0][row] = v.x; As[c * 4 + 1][row] = v.y;
        As[c * 4 + 2][row] = v.z; As[c * 4 + 3][row] = v.w;
      }
    } else {
#pragma unroll
      for (int l = 0; l < 2; ++l) {
        int flat = tid + 256 * l;
        int kk = flat >> 5, mc = flat & 31;
        const float4 v = *reinterpret_cast<const float4*>(&A[(size_t)(k0 + kk) * lda + bm + mc * 4]);
        *reinterpret_cast<float4*>(&As[kk][mc * 4]) = v;
      }
    }
    if (OPB == 0) {
#pragma unroll
      for (int l = 0; l < 2; ++l) {
        int flat = tid + 256 * l;
        int kk = flat >> 5, nc = flat & 31;
        const float4 v = *reinterpret_cast<const float4*>(&B[(size_t)(k0 + kk) * ldb + bn + nc * 4]);
        *reinterpret_cast<float4*>(&Bs[kk][nc * 4]) = v;
      }
    } else {
#pragma unroll
      for (int l = 0; l < 2; ++l) {
        int flat = tid + 256 * l;
        int row = flat >> 2, c = flat & 3;
        const float4 v = *reinterpret_cast<const float4*>(&B[(size_t)(bn + row) * ldb + k0 + c * 4]);
        Bs[c * 4 + 0][row] = v.x; Bs[c * 4 + 1][row] = v.y;
        Bs[c * 4 + 2][row] = v.z; Bs[c * 4 + 3][row] = v.w;
      }
    }
    __syncthreads();
#pragma unroll
    for (int kk = 0; kk < GBK; ++kk) {
      float a[8], b[8];
      *reinterpret_cast<float4*>(&a[0]) = *reinterpret_cast<const float4*>(&As[kk][ty * 4]);
      *reinterpret_cast<float4*>(&a[4]) = *reinterpret_cast<const float4*>(&As[kk][64 + ty * 4]);
      *reinterpret_cast<float4*>(&b[0]) = *reinterpret_cast<const float4*>(&Bs[kk][tx * 4]);
      *reinterpret_cast<float4*>(&b[4]) = *reinterpret_cast<const float4*>(&Bs[kk][64 + tx * 4]);
#pragma unroll
      for (int i = 0; i < 8; ++i)
#pragma unroll
        for (int j = 0; j < 8; ++j)
          acc[i][j] = fmaf(a[i], b[j], acc[i][j]);
    }
    __syncthreads();
  }
#pragma unroll
  for (int i = 0; i < 8; ++i) {
    int gm = bm + ((i < 4) ? (ty * 4 + i) : (64 + ty * 4 + i - 4));
#pragma unroll
    for (int jh = 0; jh < 2; ++jh) {
      int gn0 = bn + (jh ? (64 + tx * 4) : (tx * 4));
      float vv[4];
#pragma unroll
      for (int j = 0; j < 4; ++j) vv[j] = alpha * acc[i][jh * 4 + j];
      if (Add) {
        const float4 ad = *reinterpret_cast<const float4*>(&Add[(size_t)gm * ldadd + gn0]);
        vv[0] += ad.x; vv[1] += ad.y; vv[2] += ad.z; vv[3] += ad.w;
      }
      if (addI) {
#pragma unroll
        for (int j = 0; j < 4; ++j) if (gm == gn0 + j) vv[j] += 1.f;
      }
      float4 v; v.x = vv[0]; v.y = vv[1]; v.z = vv[2]; v.w = vv[3];
      *reinterpret_cast<float4*>(&C[(size_t)gm * ldc + gn0]) = v;
    }
  }
  (void)M; (void)N;
}

static void gemm_b(hipStream_t st, int opa, int opb, int M, int N, int K,
                   const float* A, int lda, size_t zsA,
                   const float* B, int ldb, size_t zsB,
                   float* C, int ldc, size_t zsC,
                   float alpha, const float* Add, int ldadd, int addI, int batch)
{
  dim3 grid(cdiv(N, TN), cdiv(M, TM), batch), blk(256);
  if (opa == 0 && opb == 0)
    gemm_kernel<0,0><<<grid, blk, 0, st>>>(M, N, K, A, lda, B, ldb, C, ldc, alpha, Add, ldadd, addI, zsA, zsB, zsC);
  else if (opa == 0 && opb == 1)
    gemm_kernel<0,1><<<grid, blk, 0, st>>>(M, N, K, A, lda, B, ldb, C, ldc, alpha, Add, ldadd, addI, zsA, zsB, zsC);
  else
    gemm_kernel<1,0><<<grid, blk, 0, st>>>(M, N, K, A, lda, B, ldb, C, ldc, alpha, Add, ldadd, addI, zsA, zsB, zsC);
}

static void gemm(hipStream_t st, int opa, int opb, int M, int N, int K,
                 const float* A, int lda, const float* B, int ldb,
                 float* C, int ldc, float alpha,
                 const float* Add, int ldadd, int addI)
{
  gemm_b(st, opa, opb, M, N, K, A, lda, 0, B, ldb, 0, C, ldc, 0, alpha, Add, ldadd, addI, 1);
}

// ---------------------------------------------------------------------------
// Matvec helpers
// ---------------------------------------------------------------------------
__global__ __launch_bounds__(256)
void mv_n_kernel(int M, int K, const float* A, int lda, const float* x, float* y)
{
  int m = (int)blockIdx.x;
  if (m >= M) return;
  const float* row = A + (size_t)m * lda;
  float s = 0.f;
  for (int k = (int)threadIdx.x; k < K; k += 256) s += row[k] * x[k];
  __shared__ float red[256];
  red[threadIdx.x] = s;
  __syncthreads();
  for (int off = 128; off > 0; off >>= 1) {
    if ((int)threadIdx.x < off) red[threadIdx.x] += red[threadIdx.x + off];
    __syncthreads();
  }
  if (threadIdx.x == 0) y[m] = red[0];
}

__global__ __launch_bounds__(256)
void mv_t_kernel(int Nrows, int Ncols, const float* A, int lda,
                 const float* x, const float* addv, float* w)
{
  int e = (int)(blockIdx.x * blockDim.x + threadIdx.x);
  if (e >= Ncols) return;
  float s = 0.f;
  for (int n = 0; n < Nrows; ++n) s += A[(size_t)n * lda + e] * x[n];
  if (addv) s += addv[e];
  w[e] = s;
}

// w0 = B^T x0, w1 = B^T x1, w2 = B^T x2 in one pass over B
__global__ __launch_bounds__(256)
void mv_t3_kernel(int Nrows, int Ncols, const float* A, int lda,
                  const float* x0, const float* x1, const float* x2,
                  float* w0, float* w1, float* w2)
{
  int e = (int)(blockIdx.x * blockDim.x + threadIdx.x);
  if (e >= Ncols) return;
  float s0 = 0.f, s1 = 0.f, s2 = 0.f;
  for (int n = 0; n < Nrows; ++n) {
    float b = A[(size_t)n * lda + e];
    s0 += b * x0[n]; s1 += b * x1[n]; s2 += b * x2[n];
  }
  w0[e] = s0; w1[e] = s1; w2[e] = s2;
}

// ---------------------------------------------------------------------------
// elementwise helpers
// ---------------------------------------------------------------------------
__global__ __launch_bounds__(256)
void scale_cols_kernel(long long total, int E, const float* B, const float* sv, float* out)
{
  long long i = (long long)blockIdx.x * blockDim.x + threadIdx.x;
  if (i < total) {
    int e = (int)(i % E);
    out[i] = B[i] * sv[e];
  }
}

__global__ __launch_bounds__(256)
void build_h_kernel(long long total, int E,
                    const float* B, const float* LB, const float* L2B,
                    const float* w0, const float* w1, const float* w2,
                    const float* a, float* H)
{
  long long i = (long long)blockIdx.x * blockDim.x + threadIdx.x;
  if (i < total) {
    int e = (int)(i % E);
    float a1 = a[1], a2 = a[2], a3 = a[3];
    float b = B[i], lb = LB[i], l2b = L2B[i];
    H[i] = w0[e] * (a1 * b + a2 * lb + a3 * l2b)
         + w1[e] * (a2 * b + a3 * lb)
         + w2[e] * (a3 * b);
  }
}

__global__ __launch_bounds__(256)
void poly_resid_kernel(int Nn, const float* a, const float* q,
                       const float* c1, const float* c2, const float* c3,
                       const float* y, float* resid)
{
  int n = (int)(blockIdx.x * blockDim.x + threadIdx.x);
  if (n < Nn)
    resid[n] = y[n] - (a[0] * q[n] + a[1] * c1[n] + a[2] * c2[n] + a[3] * c3[n]);
}

__global__ __launch_bounds__(256)
void fzero_kernel(float* p, long long n)
{
  long long i = (long long)blockIdx.x * blockDim.x + threadIdx.x;
  if (i < n) p[i] = 0.f;
}

// ---------------------------------------------------------------------------
// index handling
// ---------------------------------------------------------------------------
__global__ __launch_bounds__(256)
void conv_idx_kernel(const void* src, int n, int* dst)
{
  const unsigned* u = (const unsigned*)src;
  bool is64 = (u[1] | u[3] | u[5] | u[7]) == 0u;
  int i = (int)(blockIdx.x * blockDim.x + threadIdx.x);
  if (i < n) dst[i] = is64 ? (int)((const long long*)src)[i] : ((const int*)src)[i];
}

__global__ __launch_bounds__(256)
void fill_int_kernel(int* p, int n, int v)
{
  int i = (int)(blockIdx.x * blockDim.x + threadIdx.x);
  if (i < n) p[i] = v;
}

__global__ __launch_bounds__(256)
void scatter_inv_kernel(const int* conn, int K, int* inv)
{
  int i = (int)(blockIdx.x * blockDim.x + threadIdx.x);
  if (i < K) inv[conn[i]] = i;
}

__global__ __launch_bounds__(256)
void mask_s_kernel(int E, const float* s_upd, const int* inv, float* s2, float* outS)
{
  int e = (int)(blockIdx.x * blockDim.x + threadIdx.x);
  if (e < E) {
    float v = (inv[e] >= 0) ? s_upd[e] : 0.f;
    s2[e] = v;
    outS[e] = v;
  }
}

__global__ __launch_bounds__(256)
void gather_cols_kernel(int Nr, int Kc, int E, const float* src, const int* conn, float* dst)
{
  long long i = (long long)blockIdx.x * blockDim.x + threadIdx.x;
  if (i < (long long)Nr * Kc) {
    int n = (int)(i / Kc), c = (int)(i % Kc);
    dst[i] = src[(size_t)n * E + conn[c]];
  }
}

__global__ __launch_bounds__(256)
void gather_scc_kernel(int Kc, int E, const float* Sig, const int* conn, float* Scc)
{
  long long i = (long long)blockIdx.x * blockDim.x + threadIdx.x;
  if (i < (long long)Kc * Kc) {
    int r = (int)(i / Kc), c = (int)(i % Kc);
    Scc[i] = Sig[(size_t)conn[r] * E + conn[c]];
  }
}

__global__ __launch_bounds__(256)
void write_sigma_out_kernel(long long total, int E, const float* Small, int Kc,
                            const int* inv, float* out)
{
  long long i = (long long)blockIdx.x * blockDim.x + threadIdx.x;
  if (i < total) {
    int r = (int)(i / E), c = (int)(i % E);
    int ir = inv[r], ic = inv[c];
    out[i] = (ir >= 0 && ic >= 0) ? Small[(size_t)ir * Kc + ic] : 0.f;
  }
}

// ---------------------------------------------------------------------------
// Fused Cholesky leaf: factor 128x128 diag block (lower, rank-4 right-looking)
// AND compute invL of that block (Gauss-Jordan, column-owner threads, no
// barriers). Writes ONLY invL (to Linv at (off,off)); the factored diag block
// is not needed downstream.
// ---------------------------------------------------------------------------
__global__ __launch_bounds__(256)
void chol_leaf_kernel(const float* __restrict__ S, int lda, int off,
                      float* __restrict__ Linv, int ldi)
{
  __shared__ float T[128][132];
  __shared__ float X[128][128];
  const int tid = (int)threadIdx.x;
  const float* Ab = S + (size_t)off * lda + off;
  for (int idx = tid; idx < 128 * 32; idx += 256) {
    int r = idx >> 5, c4 = (idx & 31) << 2;
    const float4 v = *reinterpret_cast<const float4*>(&Ab[(size_t)r * lda + c4]);
    *reinterpret_cast<float4*>(&T[r][c4]) = v;
    X[r][c4 + 0] = (r == c4 + 0) ? 1.f : 0.f;
    X[r][c4 + 1] = (r == c4 + 1) ? 1.f : 0.f;
    X[r][c4 + 2] = (r == c4 + 2) ? 1.f : 0.f;
    X[r][c4 + 3] = (r == c4 + 3) ? 1.f : 0.f;
  }
  __syncthreads();
  const int g = tid >> 5, lane = tid & 31;
  for (int j0 = 0; j0 < 128; j0 += 4) {
    // panel columns j0..j0+3
    for (int t = 0; t < 4; ++t) {
      int j = j0 + t;
      if (tid < 128 && tid >= j) {
        float s = T[tid][j];
        for (int u = 0; u < t; ++u) s -= T[tid][j0 + u] * T[j][j0 + u];
        T[tid][j] = s;
      }
      __syncthreads();
      float d = sqrtf(T[j][j]);
      if (tid < 128 && tid >= j) T[tid][j] = (tid == j) ? d : T[tid][j] / d;
      __syncthreads();
    }
    // rank-4 trailing update
    for (int r = j0 + 4 + g; r < 128; r += 8) {
      const float4 lr = *reinterpret_cast<const float4*>(&T[r][j0]);
      for (int c = j0 + 4 + lane; c <= r; c += 32) {
        const float4 lc = *reinterpret_cast<const float4*>(&T[c][j0]);
        T[r][c] -= lr.x * lc.x + lr.y * lc.y + lr.z * lc.z + lr.w * lc.w;
      }
    }
    __syncthreads();
  }
  // inversion: X = L^{-1}; thread c owns column c; no barriers needed.
  if (tid < 128) {
    const int c = tid;
    for (int j0 = 0; j0 < 128; j0 += 4) {
      float s, xp0, xp1, xp2, xp3;
      s = X[j0 + 0][c];
      xp0 = s / T[j0 + 0][j0 + 0]; X[j0 + 0][c] = xp0;
      s = X[j0 + 1][c] - T[j0 + 1][j0] * xp0;
      xp1 = s / T[j0 + 1][j0 + 1]; X[j0 + 1][c] = xp1;
      s = X[j0 + 2][c] - T[j0 + 2][j0] * xp0 - T[j0 + 2][j0 + 1] * xp1;
      xp2 = s / T[j0 + 2][j0 + 2]; X[j0 + 2][c] = xp2;
      s = X[j0 + 3][c] - T[j0 + 3][j0] * xp0 - T[j0 + 3][j0 + 1] * xp1 - T[j0 + 3][j0 + 2] * xp2;
      xp3 = s / T[j0 + 3][j0 + 3]; X[j0 + 3][c] = xp3;
      for (int i = j0 + 4; i < 128; ++i) {
        const float4 lr = *reinterpret_cast<const float4*>(&T[i][j0]);
        X[i][c] -= lr.x * xp0 + lr.y * xp1 + lr.z * xp2 + lr.w * xp3;
      }
    }
  }
  __syncthreads();
  float* Ob = Linv + (size_t)off * ldi + off;
  for (int idx = tid; idx < 128 * 32; idx += 256) {
    int r = idx >> 5, c4 = (idx & 31) << 2;
    float4 v;
    v.x = X[r][c4]; v.y = X[r][c4 + 1]; v.z = X[r][c4 + 2]; v.w = X[r][c4 + 3];
    *reinterpret_cast<float4*>(&Ob[(size_t)r * ldi + c4]) = v;
  }
}

// ---------------------------------------------------------------------------
// SPD inverse: S (n x n) -> Sinv, using blocked Cholesky with GEMM panel
// solves (via leaf-inverted diag blocks), batched recursive TRTRI bisection,
// then Sinv = Linv^T Linv. S is destroyed (holds factor panels).
// ---------------------------------------------------------------------------
static void spd_inverse(hipStream_t st, float* S, float* Linv, float* Sinv, float* TT, int n)
{
  long long nn = (long long)n * n;
  fzero_kernel<<<cdiv((int)nn, 256), 256, 0, st>>>(Linv, nn);
  for (int off = 0; off < n; off += 128) {
    chol_leaf_kernel<<<1, 256, 0, st>>>(S, n, off, Linv, n);
    int mrem = n - off - 128;
    if (mrem > 0) {
      float* P = S + (size_t)(off + 128) * n + off;
      // P = P * invL11^T   (in-place: per-block row ranges disjoint)
      gemm(st, 0, 1, mrem, 128, 128, P, n, Linv + (size_t)off * (n + 1), n, P, n, 1.f, nullptr, 0, 0);
      float* Ct = S + (size_t)(off + 128) * (n + 1);
      gemm(st, 0, 1, mrem, mrem, 128, P, n, P, n, Ct, n, -1.f, Ct, n, 0);
    }
  }
  // bisection: fill lower off-diagonal blocks of Linv
  for (int m = 128; m < n; m <<= 1) {
    int pairs = n / (2 * m);
    size_t zs = (size_t)2 * m * (n + 1);
    // T_z = L21_z * invA11_z
    gemm_b(st, 0, 0, m, m, m, S + (size_t)m * n, n, zs, Linv, n, zs,
           TT, m, (size_t)m * m, 1.f, nullptr, 0, 0, pairs);
    // Linv21_z = -invA22_z * T_z
    gemm_b(st, 0, 0, m, m, m, Linv + (size_t)m * (n + 1), n, zs, TT, m, (size_t)m * m,
           Linv + (size_t)m * n, n, zs, -1.f, nullptr, 0, 0, pairs);
  }
  gemm(st, 1, 0, n, n, n, Linv, n, Linv, n, Sinv, n, 1.f, nullptr, 0, 0);
}

// ---------------------------------------------------------------------------
extern "C" void kernel_launch(void* const* d_in, const int* in_sizes, int n_in,
                              void* d_out, int out_size, void* d_ws, size_t ws_size,
                              hipStream_t stream)
{
  const float* F  = (const float*)d_in[0];
  const float* B  = (const float*)d_in[1];
  const float* V  = (const float*)d_in[2];
  const float* W  = (const float*)d_in[3];
  const float* Sg = (const float*)d_in[4];
  const float* sv = (const float*)d_in[5];
  const float* av = (const float*)d_in[6];
  const float* q  = (const float*)d_in[7];
  const float* y  = (const float*)d_in[8];
  const void*  connRaw = d_in[10];

  const int E  = in_sizes[5];
  const int Nn = in_sizes[7];
  const int Kc = in_sizes[10];

  const size_t EE = (size_t)E * E;
  const size_t NE = (size_t)Nn * E;
  const size_t NN = (size_t)Nn * Nn;
  const size_t NK = (size_t)Nn * Kc;
  const size_t KK = (size_t)Kc * Kc;

  float* ws = (float*)d_ws;
  float* EE_A = ws;
  float* EE_B = EE_A + EE;
  float* NE_1 = EE_B + EE;
  float* NE_2 = NE_1 + NE;   // also Y / TT / T10 (time-disjoint)
  float* NE_3 = NE_2 + NE;
  float* NN_1 = NE_3 + NE;   // L / S factor
  float* NN_2 = NN_1 + NN;   // Linv
  float* NN_3 = NN_2 + NN;   // Sinv
  float* vec  = NN_3 + NN;
  float* s1    = vec;            vec += E;
  float* c1    = vec;            vec += Nn;
  float* c2    = vec;            vec += Nn;
  float* c3    = vec;            vec += Nn;
  float* w0    = vec;            vec += E;
  float* w1    = vec;            vec += E;
  float* w2    = vec;            vec += E;
  float* resid = vec;            vec += Nn;
  float* s_upd = vec;            vec += E;
  float* s2    = vec;            vec += E;
  int* conn32  = (int*)vec;
  int* invc    = conn32 + Kc;

  float* outS   = (float*)d_out;   // E
  float* outSig = outS + E;        // E*E; scratch until final write
  float* EE_C   = outSig;
  float* TT     = NE_2;            // bisection temp (dead region at that time)

  const long long totNE = (long long)Nn * E;
  const long long totEE = (long long)E * E;

  // ---- stage 1 ----
  mv_n_kernel<<<E, 256, 0, stream>>>(E, E, F, E, sv, s1);                        // s1 = F s
  gemm(stream, 0, 0, E, E, E, F, E, Sg, E, EE_A, E, 1.f, nullptr, 0, 0);         // G1 = F Sigma
  gemm(stream, 0, 1, E, E, E, EE_A, E, F, E, EE_B, E, 1.f, V, E, 0);             // Sigma1 = G1 F^T + V
  scale_cols_kernel<<<cdiv((int)totNE, 256), 256, 0, stream>>>(totNE, E, B, s1, NE_1); // Bs
  gemm(stream, 0, 1, Nn, Nn, E, NE_1, E, B, E, NN_1, Nn, 1.f, nullptr, 0, 0);    // L = Bs B^T
  mv_n_kernel<<<Nn, 256, 0, stream>>>(Nn, Nn, NN_1, Nn, q, c1);
  mv_n_kernel<<<Nn, 256, 0, stream>>>(Nn, Nn, NN_1, Nn, c1, c2);
  mv_n_kernel<<<Nn, 256, 0, stream>>>(Nn, Nn, NN_1, Nn, c2, c3);
  mv_t3_kernel<<<cdiv(E, 256), 256, 0, stream>>>(Nn, E, B, E, q, c1, c2, w0, w1, w2);
  poly_resid_kernel<<<cdiv(Nn, 256), 256, 0, stream>>>(Nn, av, q, c1, c2, c3, y, resid);
  gemm(stream, 0, 0, Nn, E, Nn, NN_1, Nn, B, E, NE_1, E, 1.f, nullptr, 0, 0);    // LB
  gemm(stream, 0, 0, Nn, E, Nn, NN_1, Nn, NE_1, E, NE_2, E, 1.f, nullptr, 0, 0); // L2B
  build_h_kernel<<<cdiv((int)totNE, 256), 256, 0, stream>>>(totNE, E, B, NE_1, NE_2, w0, w1, w2, av, NE_3); // H
  gemm(stream, 0, 0, Nn, E, E, NE_3, E, EE_B, E, NE_1, E, 1.f, nullptr, 0, 0);   // T2 = H Sigma1
  gemm(stream, 0, 1, Nn, Nn, E, NE_1, E, NE_3, E, NN_1, Nn, 1.f, W, Nn, 0);      // S = T2 H^T + W
  spd_inverse(stream, NN_1, NN_2, NN_3, TT, Nn);                                 // Sinv in NN_3
  gemm(stream, 0, 0, Nn, E, Nn, NN_3, Nn, NE_1, E, NE_2, E, 1.f, nullptr, 0, 0); // Y = Sinv T2
  mv_t_kernel<<<cdiv(E, 256), 256, 0, stream>>>(Nn, E, NE_2, E, resid, s1, s_upd); // s_upd = s1 + Y^T resid
  gemm(stream, 1, 0, E, E, Nn, NE_2, E, NE_3, E, EE_A, E, -1.f, nullptr, 0, 1);  // ImKH = I - Y^T H
  gemm(stream, 0, 0, E, E, E, EE_A, E, EE_B, E, EE_C, E, 1.f, nullptr, 0, 0);    // T3 = ImKH Sigma1
  gemm(stream, 0, 1, E, E, E, EE_C, E, EE_A, E, EE_B, E, 1.f, nullptr, 0, 0);    // T4 = T3 ImKH^T
  gemm(stream, 1, 0, E, Nn, Nn, NE_2, E, W, Nn, NE_1, Nn, 1.f, nullptr, 0, 0);   // T5 = Y^T W
  gemm(stream, 0, 0, E, E, Nn, NE_1, Nn, NE_2, E, EE_B, E, 1.f, EE_B, E, 0);     // Sigma2 = T5 Y + T4

  // ---- masking / stage 2 ----
  conv_idx_kernel<<<cdiv(Kc, 256), 256, 0, stream>>>(connRaw, Kc, conn32);
  fill_int_kernel<<<cdiv(E, 256), 256, 0, stream>>>(invc, E, -1);
  scatter_inv_kernel<<<cdiv(Kc, 256), 256, 0, stream>>>(conn32, Kc, invc);
  mask_s_kernel<<<cdiv(E, 256), 256, 0, stream>>>(E, s_upd, invc, s2, outS);

  scale_cols_kernel<<<cdiv((int)totNE, 256), 256, 0, stream>>>(totNE, E, B, s2, NE_1); // Bs2
  gemm(stream, 0, 1, Nn, Nn, E, NE_1, E, B, E, NN_1, Nn, 1.f, nullptr, 0, 0);    // L2
  mv_n_kernel<<<Nn, 256, 0, stream>>>(Nn, Nn, NN_1, Nn, q, c1);
  mv_n_kernel<<<Nn, 256, 0, stream>>>(Nn, Nn, NN_1, Nn, c1, c2);
  mv_t3_kernel<<<cdiv(E, 256), 256, 0, stream>>>(Nn, E, B, E, q, c1, c2, w0, w1, w2);
  gemm(stream, 0, 0, Nn, E, Nn, NN_1, Nn, B, E, NE_1, E, 1.f, nullptr, 0, 0);    // L2 B
  gemm(stream, 0, 0, Nn, E, Nn, NN_1, Nn, NE_1, E, NE_2, E, 1.f, nullptr, 0, 0); // L2^2 B
  build_h_kernel<<<cdiv((int)totNE, 256), 256, 0, stream>>>(totNE, E, B, NE_1, NE_2, w0, w1, w2, av, NE_3); // H2full
  gather_cols_kernel<<<cdiv((int)NK, 256), 256, 0, stream>>>(Nn, Kc, E, NE_3, conn32, EE_A);        // H2 (Nn x Kc)
  gather_scc_kernel<<<cdiv((int)KK, 256), 256, 0, stream>>>(Kc, E, EE_B, conn32, EE_A + NK);        // Scc (Kc x Kc)
  gemm(stream, 0, 0, Nn, Kc, Kc, EE_A, Kc, EE_A + NK, Kc, EE_B, Kc, 1.f, nullptr, 0, 0); // T7 = H2 Scc
  gemm(stream, 0, 1, Nn, Nn, Kc, EE_B, Kc, EE_A, Kc, NN_1, Nn, 1.f, W, Nn, 0);   // S2 = T7 H2^T + W
  spd_inverse(stream, NN_1, NN_2, NN_3, TT, Nn);                                 // Sinv2 in NN_3
  gemm(stream, 0, 0, Nn, Kc, Nn, NN_3, Nn, EE_B, Kc, NE_1, Kc, 1.f, nullptr, 0, 0);  // Y2 = Sinv2 T7
  gemm(stream, 1, 0, Kc, Kc, Nn, NE_1, Kc, EE_A, Kc, EE_C, Kc, -1.f, nullptr, 0, 1); // ImKH2 = I - Y2^T H2
  gemm(stream, 0, 0, Kc, Kc, Kc, EE_C, Kc, EE_A + NK, Kc, EE_C + KK, Kc, 1.f, nullptr, 0, 0); // T8 = ImKH2 Scc
  gemm(stream, 0, 1, Kc, Kc, Kc, EE_C + KK, Kc, EE_C, Kc, EE_A + NK, Kc, 1.f, nullptr, 0, 0); // T9 = T8 ImKH2^T
  gemm(stream, 1, 0, Kc, Nn, Nn, NE_1, Kc, W, Nn, NE_2, Nn, 1.f, nullptr, 0, 0); // T10 = Y2^T W
  gemm(stream, 0, 0, Kc, Kc, Nn, NE_2, Nn, NE_1, Kc, EE_A + NK, Kc, 1.f, EE_A + NK, Kc, 0); // Small = T10 Y2 + T9

  write_sigma_out_kernel<<<cdiv((int)totEE, 256), 256, 0, stream>>>(totEE, E, EE_A + NK, Kc, invc, outSig);

  (void)n_in; (void)out_size; (void)ws_size;
}

// Round 5
// 5901.988 us; speedup vs baseline: 2.9394x; 1.4239x over previous
//
#include <hip/hip_runtime.h>

static inline int cdiv(int a, int b) { return (a + b - 1) / b; }

#define GBK 16

// ---------------------------------------------------------------------------
// GEMM: C = alpha * opA(A) opB(B) + (Add?Add:0) + (addI?I:0)
// OPA==0: A is MxK row-major.  OPA==1: A physical KxM; opA[m,k]=A[k*lda+m]
// OPB==0: B is KxN row-major.  OPB==1: B physical NxK; opB[k,n]=B[n*ldb+k]
// Batched over blockIdx.z via element strides zsA/zsB/zsC.
// TMp=TNp=128 -> 512 threads; TMp=TNp=64 -> 256 threads.
// Double-buffered LDS, one barrier per K-step, register prefetch.
// REQUIRES: M,N multiples of TMp/TNp; K multiple of 16; 16B-aligned pointers.
// ---------------------------------------------------------------------------
template<int TMp, int TNp, int OPA, int OPB>
__global__ void __launch_bounds__((TMp == 128) ? 512 : 256)
gemm_kernel(int M, int N, int K,
            const float* __restrict__ A, int lda,
            const float* __restrict__ B, int ldb,
            float* __restrict__ C, int ldc,
            float alpha,
            const float* __restrict__ Add, int ldadd, int addI,
            size_t zsA, size_t zsB, size_t zsC)
{
  constexpr int GN = TNp / 64;          // column groups (2 or 1)
  constexpr int PAD = 4;
  A += (size_t)blockIdx.z * zsA;
  B += (size_t)blockIdx.z * zsB;
  C += (size_t)blockIdx.z * zsC;
  __shared__ float As[2][GBK][TMp + PAD];
  __shared__ float Bs[2][GBK][TNp + PAD];
  const int tid = (int)threadIdx.x;
  const int tx = tid & 15;
  const int ty = tid >> 4;
  const int bm = (int)blockIdx.y * TMp;
  const int bn = (int)blockIdx.x * TNp;

  // staging indices (one float4 per thread per operand)
  const int arow = tid >> 2, aq = tid & 3;                 // OPA==0
  const int akk = tid / (TMp / 4), amc = tid % (TMp / 4);  // OPA==1
  const int bkk = tid / (TNp / 4), bnc = tid % (TNp / 4);  // OPB==0
  const int brow = tid >> 2, bq = tid & 3;                 // OPB==1

  float4 ra, rb;
  auto loadA = [&](int k0) {
    if (OPA == 0) ra = *reinterpret_cast<const float4*>(&A[(size_t)(bm + arow) * lda + k0 + aq * 4]);
    else          ra = *reinterpret_cast<const float4*>(&A[(size_t)(k0 + akk) * lda + bm + amc * 4]);
  };
  auto storeA = [&](int buf) {
    if (OPA == 0) {
      As[buf][aq * 4 + 0][arow] = ra.x; As[buf][aq * 4 + 1][arow] = ra.y;
      As[buf][aq * 4 + 2][arow] = ra.z; As[buf][aq * 4 + 3][arow] = ra.w;
    } else {
      *reinterpret_cast<float4*>(&As[buf][akk][amc * 4]) = ra;
    }
  };
  auto loadB = [&](int k0) {
    if (OPB == 0) rb = *reinterpret_cast<const float4*>(&B[(size_t)(k0 + bkk) * ldb + bn + bnc * 4]);
    else          rb = *reinterpret_cast<const float4*>(&B[(size_t)(bn + brow) * ldb + k0 + bq * 4]);
  };
  auto storeB = [&](int buf) {
    if (OPB == 0) {
      *reinterpret_cast<float4*>(&Bs[buf][bkk][bnc * 4]) = rb;
    } else {
      Bs[buf][bq * 4 + 0][brow] = rb.x; Bs[buf][bq * 4 + 1][brow] = rb.y;
      Bs[buf][bq * 4 + 2][brow] = rb.z; Bs[buf][bq * 4 + 3][brow] = rb.w;
    }
  };

  float acc[4][GN * 4];
#pragma unroll
  for (int i = 0; i < 4; ++i)
#pragma unroll
    for (int j = 0; j < GN * 4; ++j) acc[i][j] = 0.f;

  const int nk = K / GBK;
  loadA(0); loadB(0); storeA(0); storeB(0);
  __syncthreads();

  for (int t = 0; t < nk; ++t) {
    const int cur = t & 1;
    if (t + 1 < nk) { loadA((t + 1) * GBK); loadB((t + 1) * GBK); }
#pragma unroll
    for (int kk = 0; kk < GBK; ++kk) {
      float a[4], b[GN * 4];
      *reinterpret_cast<float4*>(a) = *reinterpret_cast<const float4*>(&As[cur][kk][ty * 4]);
#pragma unroll
      for (int g = 0; g < GN; ++g)
        *reinterpret_cast<float4*>(&b[g * 4]) = *reinterpret_cast<const float4*>(&Bs[cur][kk][g * 64 + tx * 4]);
#pragma unroll
      for (int i = 0; i < 4; ++i)
#pragma unroll
        for (int j = 0; j < GN * 4; ++j)
          acc[i][j] = fmaf(a[i], b[j], acc[i][j]);
    }
    if (t + 1 < nk) { storeA(cur ^ 1); storeB(cur ^ 1); }
    __syncthreads();
  }

#pragma unroll
  for (int i = 0; i < 4; ++i) {
    const int gm = bm + ty * 4 + i;
#pragma unroll
    for (int g = 0; g < GN; ++g) {
      const int gn0 = bn + g * 64 + tx * 4;
      float vv[4];
#pragma unroll
      for (int j = 0; j < 4; ++j) vv[j] = alpha * acc[i][g * 4 + j];
      if (Add) {
        const float4 ad = *reinterpret_cast<const float4*>(&Add[(size_t)gm * ldadd + gn0]);
        vv[0] += ad.x; vv[1] += ad.y; vv[2] += ad.z; vv[3] += ad.w;
      }
      if (addI) {
#pragma unroll
        for (int j = 0; j < 4; ++j) if (gm == gn0 + j) vv[j] += 1.f;
      }
      float4 v; v.x = vv[0]; v.y = vv[1]; v.z = vv[2]; v.w = vv[3];
      *reinterpret_cast<float4*>(&C[(size_t)gm * ldc + gn0]) = v;
    }
  }
  (void)M; (void)N;
}

static void gemm_b(hipStream_t st, int opa, int opb, int M, int N, int K,
                   const float* A, int lda, size_t zsA,
                   const float* B, int ldb, size_t zsB,
                   float* C, int ldc, size_t zsC,
                   float alpha, const float* Add, int ldadd, int addI, int batch)
{
  const bool big = ((long long)M * (long long)N >= 4194304LL) && (M % 128 == 0) && (N % 128 == 0);
  if (big) {
    dim3 grid(N / 128, M / 128, batch), blk(512);
    if (opa == 0 && opb == 0)
      gemm_kernel<128,128,0,0><<<grid, blk, 0, st>>>(M, N, K, A, lda, B, ldb, C, ldc, alpha, Add, ldadd, addI, zsA, zsB, zsC);
    else if (opa == 0 && opb == 1)
      gemm_kernel<128,128,0,1><<<grid, blk, 0, st>>>(M, N, K, A, lda, B, ldb, C, ldc, alpha, Add, ldadd, addI, zsA, zsB, zsC);
    else
      gemm_kernel<128,128,1,0><<<grid, blk, 0, st>>>(M, N, K, A, lda, B, ldb, C, ldc, alpha, Add, ldadd, addI, zsA, zsB, zsC);
  } else {
    dim3 grid(N / 64, M / 64, batch), blk(256);
    if (opa == 0 && opb == 0)
      gemm_kernel<64,64,0,0><<<grid, blk, 0, st>>>(M, N, K, A, lda, B, ldb, C, ldc, alpha, Add, ldadd, addI, zsA, zsB, zsC);
    else if (opa == 0 && opb == 1)
      gemm_kernel<64,64,0,1><<<grid, blk, 0, st>>>(M, N, K, A, lda, B, ldb, C, ldc, alpha, Add, ldadd, addI, zsA, zsB, zsC);
    else
      gemm_kernel<64,64,1,0><<<grid, blk, 0, st>>>(M, N, K, A, lda, B, ldb, C, ldc, alpha, Add, ldadd, addI, zsA, zsB, zsC);
  }
}

static void gemm(hipStream_t st, int opa, int opb, int M, int N, int K,
                 const float* A, int lda, const float* B, int ldb,
                 float* C, int ldc, float alpha,
                 const float* Add, int ldadd, int addI)
{
  gemm_b(st, opa, opb, M, N, K, A, lda, 0, B, ldb, 0, C, ldc, 0, alpha, Add, ldadd, addI, 1);
}

// ---------------------------------------------------------------------------
// Matvec helpers
// ---------------------------------------------------------------------------
__global__ __launch_bounds__(256)
void mv_n_kernel(int M, int K, const float* A, int lda, const float* x, float* y)
{
  int m = (int)blockIdx.x;
  if (m >= M) return;
  const float* row = A + (size_t)m * lda;
  float s = 0.f;
  for (int k = (int)threadIdx.x; k < K; k += 256) s += row[k] * x[k];
  __shared__ float red[256];
  red[threadIdx.x] = s;
  __syncthreads();
  for (int off = 128; off > 0; off >>= 1) {
    if ((int)threadIdx.x < off) red[threadIdx.x] += red[threadIdx.x + off];
    __syncthreads();
  }
  if (threadIdx.x == 0) y[m] = red[0];
}

__global__ __launch_bounds__(256)
void mv_t_kernel(int Nrows, int Ncols, const float* A, int lda,
                 const float* x, const float* addv, float* w)
{
  int e = (int)(blockIdx.x * blockDim.x + threadIdx.x);
  if (e >= Ncols) return;
  float s = 0.f;
  for (int n = 0; n < Nrows; ++n) s += A[(size_t)n * lda + e] * x[n];
  if (addv) s += addv[e];
  w[e] = s;
}

// w0 = B^T x0, w1 = B^T x1, w2 = B^T x2 in one pass over B
__global__ __launch_bounds__(256)
void mv_t3_kernel(int Nrows, int Ncols, const float* A, int lda,
                  const float* x0, const float* x1, const float* x2,
                  float* w0, float* w1, float* w2)
{
  int e = (int)(blockIdx.x * blockDim.x + threadIdx.x);
  if (e >= Ncols) return;
  float s0 = 0.f, s1 = 0.f, s2 = 0.f;
  for (int n = 0; n < Nrows; ++n) {
    float b = A[(size_t)n * lda + e];
    s0 += b * x0[n]; s1 += b * x1[n]; s2 += b * x2[n];
  }
  w0[e] = s0; w1[e] = s1; w2[e] = s2;
}

// ---------------------------------------------------------------------------
// elementwise helpers
// ---------------------------------------------------------------------------
__global__ __launch_bounds__(256)
void scale_cols_kernel(long long total, int E, const float* B, const float* sv, float* out)
{
  long long i = (long long)blockIdx.x * blockDim.x + threadIdx.x;
  if (i < total) {
    int e = (int)(i % E);
    out[i] = B[i] * sv[e];
  }
}

__global__ __launch_bounds__(256)
void build_h_kernel(long long total, int E,
                    const float* B, const float* LB, const float* L2B,
                    const float* w0, const float* w1, const float* w2,
                    const float* a, float* H)
{
  long long i = (long long)blockIdx.x * blockDim.x + threadIdx.x;
  if (i < total) {
    int e = (int)(i % E);
    float a1 = a[1], a2 = a[2], a3 = a[3];
    float b = B[i], lb = LB[i], l2b = L2B[i];
    H[i] = w0[e] * (a1 * b + a2 * lb + a3 * l2b)
         + w1[e] * (a2 * b + a3 * lb)
         + w2[e] * (a3 * b);
  }
}

__global__ __launch_bounds__(256)
void poly_resid_kernel(int Nn, const float* a, const float* q,
                       const float* c1, const float* c2, const float* c3,
                       const float* y, float* resid)
{
  int n = (int)(blockIdx.x * blockDim.x + threadIdx.x);
  if (n < Nn)
    resid[n] = y[n] - (a[0] * q[n] + a[1] * c1[n] + a[2] * c2[n] + a[3] * c3[n]);
}

__global__ __launch_bounds__(256)
void fzero_kernel(float* p, long long n)
{
  long long i = (long long)blockIdx.x * blockDim.x + threadIdx.x;
  if (i < n) p[i] = 0.f;
}

// ---------------------------------------------------------------------------
// index handling
// ---------------------------------------------------------------------------
__global__ __launch_bounds__(256)
void conv_idx_kernel(const void* src, int n, int* dst)
{
  const unsigned* u = (const unsigned*)src;
  bool is64 = (u[1] | u[3] | u[5] | u[7]) == 0u;
  int i = (int)(blockIdx.x * blockDim.x + threadIdx.x);
  if (i < n) dst[i] = is64 ? (int)((const long long*)src)[i] : ((const int*)src)[i];
}

__global__ __launch_bounds__(256)
void fill_int_kernel(int* p, int n, int v)
{
  int i = (int)(blockIdx.x * blockDim.x + threadIdx.x);
  if (i < n) p[i] = v;
}

__global__ __launch_bounds__(256)
void scatter_inv_kernel(const int* conn, int K, int* inv)
{
  int i = (int)(blockIdx.x * blockDim.x + threadIdx.x);
  if (i < K) inv[conn[i]] = i;
}

__global__ __launch_bounds__(256)
void mask_s_kernel(int E, const float* s_upd, const int* inv, float* s2, float* outS)
{
  int e = (int)(blockIdx.x * blockDim.x + threadIdx.x);
  if (e < E) {
    float v = (inv[e] >= 0) ? s_upd[e] : 0.f;
    s2[e] = v;
    outS[e] = v;
  }
}

__global__ __launch_bounds__(256)
void gather_cols_kernel(int Nr, int Kc, int E, const float* src, const int* conn, float* dst)
{
  long long i = (long long)blockIdx.x * blockDim.x + threadIdx.x;
  if (i < (long long)Nr * Kc) {
    int n = (int)(i / Kc), c = (int)(i % Kc);
    dst[i] = src[(size_t)n * E + conn[c]];
  }
}

__global__ __launch_bounds__(256)
void gather_scc_kernel(int Kc, int E, const float* Sig, const int* conn, float* Scc)
{
  long long i = (long long)blockIdx.x * blockDim.x + threadIdx.x;
  if (i < (long long)Kc * Kc) {
    int r = (int)(i / Kc), c = (int)(i % Kc);
    Scc[i] = Sig[(size_t)conn[r] * E + conn[c]];
  }
}

__global__ __launch_bounds__(256)
void write_sigma_out_kernel(long long total, int E, const float* Small, int Kc,
                            const int* inv, float* out)
{
  long long i = (long long)blockIdx.x * blockDim.x + threadIdx.x;
  if (i < total) {
    int r = (int)(i / E), c = (int)(i % E);
    int ir = inv[r], ic = inv[c];
    out[i] = (ir >= 0 && ic >= 0) ? Small[(size_t)ir * Kc + ic] : 0.f;
  }
}

// ---------------------------------------------------------------------------
// Fused Cholesky leaf: factor 128x128 diag block (lower, rank-4 right-looking)
// AND compute invL of that block (column-owner threads, no barriers).
// Writes ONLY invL (to Linv at (off,off)).
// ---------------------------------------------------------------------------
__global__ __launch_bounds__(256)
void chol_leaf_kernel(const float* __restrict__ S, int lda, int off,
                      float* __restrict__ Linv, int ldi)
{
  __shared__ float T[128][132];
  __shared__ float X[128][128];
  const int tid = (int)threadIdx.x;
  const float* Ab = S + (size_t)off * lda + off;
  for (int idx = tid; idx < 128 * 32; idx += 256) {
    int r = idx >> 5, c4 = (idx & 31) << 2;
    const float4 v = *reinterpret_cast<const float4*>(&Ab[(size_t)r * lda + c4]);
    *reinterpret_cast<float4*>(&T[r][c4]) = v;
    X[r][c4 + 0] = (r == c4 + 0) ? 1.f : 0.f;
    X[r][c4 + 1] = (r == c4 + 1) ? 1.f : 0.f;
    X[r][c4 + 2] = (r == c4 + 2) ? 1.f : 0.f;
    X[r][c4 + 3] = (r == c4 + 3) ? 1.f : 0.f;
  }
  __syncthreads();
  const int g = tid >> 5, lane = tid & 31;
  for (int j0 = 0; j0 < 128; j0 += 4) {
    for (int t = 0; t < 4; ++t) {
      int j = j0 + t;
      if (tid < 128 && tid >= j) {
        float s = T[tid][j];
        for (int u = 0; u < t; ++u) s -= T[tid][j0 + u] * T[j][j0 + u];
        T[tid][j] = s;
      }
      __syncthreads();
      float d = sqrtf(T[j][j]);
      if (tid < 128 && tid >= j) T[tid][j] = (tid == j) ? d : T[tid][j] / d;
      __syncthreads();
    }
    for (int r = j0 + 4 + g; r < 128; r += 8) {
      const float4 lr = *reinterpret_cast<const float4*>(&T[r][j0]);
      for (int c = j0 + 4 + lane; c <= r; c += 32) {
        const float4 lc = *reinterpret_cast<const float4*>(&T[c][j0]);
        T[r][c] -= lr.x * lc.x + lr.y * lc.y + lr.z * lc.z + lr.w * lc.w;
      }
    }
    __syncthreads();
  }
  if (tid < 128) {
    const int c = tid;
    for (int j0 = 0; j0 < 128; j0 += 4) {
      float s, xp0, xp1, xp2, xp3;
      s = X[j0 + 0][c];
      xp0 = s / T[j0 + 0][j0 + 0]; X[j0 + 0][c] = xp0;
      s = X[j0 + 1][c] - T[j0 + 1][j0] * xp0;
      xp1 = s / T[j0 + 1][j0 + 1]; X[j0 + 1][c] = xp1;
      s = X[j0 + 2][c] - T[j0 + 2][j0] * xp0 - T[j0 + 2][j0 + 1] * xp1;
      xp2 = s / T[j0 + 2][j0 + 2]; X[j0 + 2][c] = xp2;
      s = X[j0 + 3][c] - T[j0 + 3][j0] * xp0 - T[j0 + 3][j0 + 1] * xp1 - T[j0 + 3][j0 + 2] * xp2;
      xp3 = s / T[j0 + 3][j0 + 3]; X[j0 + 3][c] = xp3;
      for (int i = j0 + 4; i < 128; ++i) {
        const float4 lr = *reinterpret_cast<const float4*>(&T[i][j0]);
        X[i][c] -= lr.x * xp0 + lr.y * xp1 + lr.z * xp2 + lr.w * xp3;
      }
    }
  }
  __syncthreads();
  float* Ob = Linv + (size_t)off * ldi + off;
  for (int idx = tid; idx < 128 * 32; idx += 256) {
    int r = idx >> 5, c4 = (idx & 31) << 2;
    float4 v;
    v.x = X[r][c4]; v.y = X[r][c4 + 1]; v.z = X[r][c4 + 2]; v.w = X[r][c4 + 3];
    *reinterpret_cast<float4*>(&Ob[(size_t)r * ldi + c4]) = v;
  }
}

// ---------------------------------------------------------------------------
// SPD inverse: S (n x n) -> Sinv. S is destroyed (holds factor panels).
// ---------------------------------------------------------------------------
static void spd_inverse(hipStream_t st, float* S, float* Linv, float* Sinv, float* TT, int n)
{
  long long nn = (long long)n * n;
  fzero_kernel<<<cdiv((int)nn, 256), 256, 0, st>>>(Linv, nn);
  for (int off = 0; off < n; off += 128) {
    chol_leaf_kernel<<<1, 256, 0, st>>>(S, n, off, Linv, n);
    int mrem = n - off - 128;
    if (mrem > 0) {
      float* P = S + (size_t)(off + 128) * n + off;
      gemm(st, 0, 1, mrem, 128, 128, P, n, Linv + (size_t)off * (n + 1), n, P, n, 1.f, nullptr, 0, 0);
      float* Ct = S + (size_t)(off + 128) * (n + 1);
      gemm(st, 0, 1, mrem, mrem, 128, P, n, P, n, Ct, n, -1.f, Ct, n, 0);
    }
  }
  for (int m = 128; m < n; m <<= 1) {
    int pairs = n / (2 * m);
    size_t zs = (size_t)2 * m * (n + 1);
    gemm_b(st, 0, 0, m, m, m, S + (size_t)m * n, n, zs, Linv, n, zs,
           TT, m, (size_t)m * m, 1.f, nullptr, 0, 0, pairs);
    gemm_b(st, 0, 0, m, m, m, Linv + (size_t)m * (n + 1), n, zs, TT, m, (size_t)m * m,
           Linv + (size_t)m * n, n, zs, -1.f, nullptr, 0, 0, pairs);
  }
  gemm(st, 1, 0, n, n, n, Linv, n, Linv, n, Sinv, n, 1.f, nullptr, 0, 0);
}

// ---------------------------------------------------------------------------
extern "C" void kernel_launch(void* const* d_in, const int* in_sizes, int n_in,
                              void* d_out, int out_size, void* d_ws, size_t ws_size,
                              hipStream_t stream)
{
  const float* F  = (const float*)d_in[0];
  const float* B  = (const float*)d_in[1];
  const float* V  = (const float*)d_in[2];
  const float* W  = (const float*)d_in[3];
  const float* Sg = (const float*)d_in[4];
  const float* sv = (const float*)d_in[5];
  const float* av = (const float*)d_in[6];
  const float* q  = (const float*)d_in[7];
  const float* y  = (const float*)d_in[8];
  const void*  connRaw = d_in[10];

  const int E  = in_sizes[5];
  const int Nn = in_sizes[7];
  const int Kc = in_sizes[10];

  const size_t EE = (size_t)E * E;
  const size_t NE = (size_t)Nn * E;
  const size_t NN = (size_t)Nn * Nn;
  const size_t NK = (size_t)Nn * Kc;
  const size_t KK = (size_t)Kc * Kc;

  float* ws = (float*)d_ws;
  float* EE_A = ws;
  float* EE_B = EE_A + EE;
  float* NE_1 = EE_B + EE;
  float* NE_2 = NE_1 + NE;   // also Y / TT / T10 (time-disjoint)
  float* NE_3 = NE_2 + NE;
  float* NN_1 = NE_3 + NE;   // L / S factor
  float* NN_2 = NN_1 + NN;   // Linv
  float* NN_3 = NN_2 + NN;   // Sinv
  float* vec  = NN_3 + NN;
  float* s1    = vec;            vec += E;
  float* c1    = vec;            vec += Nn;
  float* c2    = vec;            vec += Nn;
  float* c3    = vec;            vec += Nn;
  float* w0    = vec;            vec += E;
  float* w1    = vec;            vec += E;
  float* w2    = vec;            vec += E;
  float* resid = vec;            vec += Nn;
  float* s_upd = vec;            vec += E;
  float* s2    = vec;            vec += E;
  int* conn32  = (int*)vec;
  int* invc    = conn32 + Kc;

  float* outS   = (float*)d_out;   // E
  float* outSig = outS + E;        // E*E; scratch until final write
  float* EE_C   = outSig;
  float* TT     = NE_2;            // bisection temp (dead region at that time)

  const long long totNE = (long long)Nn * E;
  const long long totEE = (long long)E * E;

  // ---- stage 1 ----
  mv_n_kernel<<<E, 256, 0, stream>>>(E, E, F, E, sv, s1);                        // s1 = F s
  gemm(stream, 0, 0, E, E, E, F, E, Sg, E, EE_A, E, 1.f, nullptr, 0, 0);         // G1 = F Sigma
  gemm(stream, 0, 1, E, E, E, EE_A, E, F, E, EE_B, E, 1.f, V, E, 0);             // Sigma1 = G1 F^T + V
  scale_cols_kernel<<<cdiv((int)totNE, 256), 256, 0, stream>>>(totNE, E, B, s1, NE_1); // Bs
  gemm(stream, 0, 1, Nn, Nn, E, NE_1, E, B, E, NN_1, Nn, 1.f, nullptr, 0, 0);    // L = Bs B^T
  mv_n_kernel<<<Nn, 256, 0, stream>>>(Nn, Nn, NN_1, Nn, q, c1);
  mv_n_kernel<<<Nn, 256, 0, stream>>>(Nn, Nn, NN_1, Nn, c1, c2);
  mv_n_kernel<<<Nn, 256, 0, stream>>>(Nn, Nn, NN_1, Nn, c2, c3);
  mv_t3_kernel<<<cdiv(E, 256), 256, 0, stream>>>(Nn, E, B, E, q, c1, c2, w0, w1, w2);
  poly_resid_kernel<<<cdiv(Nn, 256), 256, 0, stream>>>(Nn, av, q, c1, c2, c3, y, resid);
  gemm(stream, 0, 0, Nn, E, Nn, NN_1, Nn, B, E, NE_1, E, 1.f, nullptr, 0, 0);    // LB
  gemm(stream, 0, 0, Nn, E, Nn, NN_1, Nn, NE_1, E, NE_2, E, 1.f, nullptr, 0, 0); // L2B
  build_h_kernel<<<cdiv((int)totNE, 256), 256, 0, stream>>>(totNE, E, B, NE_1, NE_2, w0, w1, w2, av, NE_3); // H
  gemm(stream, 0, 0, Nn, E, E, NE_3, E, EE_B, E, NE_1, E, 1.f, nullptr, 0, 0);   // T2 = H Sigma1
  gemm(stream, 0, 1, Nn, Nn, E, NE_1, E, NE_3, E, NN_1, Nn, 1.f, W, Nn, 0);      // S = T2 H^T + W
  spd_inverse(stream, NN_1, NN_2, NN_3, TT, Nn);                                 // Sinv in NN_3
  gemm(stream, 0, 0, Nn, E, Nn, NN_3, Nn, NE_1, E, NE_2, E, 1.f, nullptr, 0, 0); // Y = Sinv T2
  mv_t_kernel<<<cdiv(E, 256), 256, 0, stream>>>(Nn, E, NE_2, E, resid, s1, s_upd); // s_upd = s1 + Y^T resid
  gemm(stream, 1, 0, E, E, Nn, NE_2, E, NE_3, E, EE_A, E, -1.f, nullptr, 0, 1);  // ImKH = I - Y^T H
  gemm(stream, 0, 0, E, E, E, EE_A, E, EE_B, E, EE_C, E, 1.f, nullptr, 0, 0);    // T3 = ImKH Sigma1
  gemm(stream, 0, 1, E, E, E, EE_C, E, EE_A, E, EE_B, E, 1.f, nullptr, 0, 0);    // T4 = T3 ImKH^T
  gemm(stream, 1, 0, E, Nn, Nn, NE_2, E, W, Nn, NE_1, Nn, 1.f, nullptr, 0, 0);   // T5 = Y^T W
  gemm(stream, 0, 0, E, E, Nn, NE_1, Nn, NE_2, E, EE_B, E, 1.f, EE_B, E, 0);     // Sigma2 = T5 Y + T4

  // ---- masking / stage 2 ----
  conv_idx_kernel<<<cdiv(Kc, 256), 256, 0, stream>>>(connRaw, Kc, conn32);
  fill_int_kernel<<<cdiv(E, 256), 256, 0, stream>>>(invc, E, -1);
  scatter_inv_kernel<<<cdiv(Kc, 256), 256, 0, stream>>>(conn32, Kc, invc);
  mask_s_kernel<<<cdiv(E, 256), 256, 0, stream>>>(E, s_upd, invc, s2, outS);

  scale_cols_kernel<<<cdiv((int)totNE, 256), 256, 0, stream>>>(totNE, E, B, s2, NE_1); // Bs2
  gemm(stream, 0, 1, Nn, Nn, E, NE_1, E, B, E, NN_1, Nn, 1.f, nullptr, 0, 0);    // L2
  mv_n_kernel<<<Nn, 256, 0, stream>>>(Nn, Nn, NN_1, Nn, q, c1);
  mv_n_kernel<<<Nn, 256, 0, stream>>>(Nn, Nn, NN_1, Nn, c1, c2);
  mv_t3_kernel<<<cdiv(E, 256), 256, 0, stream>>>(Nn, E, B, E, q, c1, c2, w0, w1, w2);
  gemm(stream, 0, 0, Nn, E, Nn, NN_1, Nn, B, E, NE_1, E, 1.f, nullptr, 0, 0);    // L2 B
  gemm(stream, 0, 0, Nn, E, Nn, NN_1, Nn, NE_1, E, NE_2, E, 1.f, nullptr, 0, 0); // L2^2 B
  build_h_kernel<<<cdiv((int)totNE, 256), 256, 0, stream>>>(totNE, E, B, NE_1, NE_2, w0, w1, w2, av, NE_3); // H2full
  gather_cols_kernel<<<cdiv((int)NK, 256), 256, 0, stream>>>(Nn, Kc, E, NE_3, conn32, EE_A);        // H2 (Nn x Kc)
  gather_scc_kernel<<<cdiv((int)KK, 256), 256, 0, stream>>>(Kc, E, EE_B, conn32, EE_A + NK);        // Scc (Kc x Kc)
  gemm(stream, 0, 0, Nn, Kc, Kc, EE_A, Kc, EE_A + NK, Kc, EE_B, Kc, 1.f, nullptr, 0, 0); // T7 = H2 Scc
  gemm(stream, 0, 1, Nn, Nn, Kc, EE_B, Kc, EE_A, Kc, NN_1, Nn, 1.f, W, Nn, 0);   // S2 = T7 H2^T + W
  spd_inverse(stream, NN_1, NN_2, NN_3, TT, Nn);                                 // Sinv2 in NN_3
  gemm(stream, 0, 0, Nn, Kc, Nn, NN_3, Nn, EE_B, Kc, NE_1, Kc, 1.f, nullptr, 0, 0);  // Y2 = Sinv2 T7
  gemm(stream, 1, 0, Kc, Kc, Nn, NE_1, Kc, EE_A, Kc, EE_C, Kc, -1.f, nullptr, 0, 1); // ImKH2 = I - Y2^T H2
  gemm(stream, 0, 0, Kc, Kc, Kc, EE_C, Kc, EE_A + NK, Kc, EE_C + KK, Kc, 1.f, nullptr, 0, 0); // T8 = ImKH2 Scc
  gemm(stream, 0, 1, Kc, Kc, Kc, EE_C + KK, Kc, EE_C, Kc, EE_A + NK, Kc, 1.f, nullptr, 0, 0); // T9 = T8 ImKH2^T
  gemm(stream, 1, 0, Kc, Nn, Nn, NE_1, Kc, W, Nn, NE_2, Nn, 1.f, nullptr, 0, 0); // T10 = Y2^T W
  gemm(stream, 0, 0, Kc, Kc, Nn, NE_2, Nn, NE_1, Kc, EE_A + NK, Kc, 1.f, EE_A + NK, Kc, 0); // Small = T10 Y2 + T9

  write_sigma_out_kernel<<<cdiv((int)totEE, 256), 256, 0, stream>>>(totEE, E, EE_A + NK, Kc, invc, outSig);

  (void)n_in; (void)out_size; (void)ws_size;
}

// Round 6
// 5806.277 us; speedup vs baseline: 2.9878x; 1.0165x over previous
//
#include <hip/hip_runtime.h>

static inline int cdiv(int a, int b) { return (a + b - 1) / b; }

#define GBK 16

// split-K partial workspace (set per kernel_launch; deterministic)
static float* g_ps = nullptr;
static long long g_ps_cap = 0;   // capacity in floats
static int g_ps_ok = 0;

// ---------------------------------------------------------------------------
// GEMM: C = alpha * opA(A) opB(B) + (Add?Add:0) + (addI?I:0)
// OPA==0: A is MxK row-major.  OPA==1: A physical KxM; opA[m,k]=A[k*lda+m]
// OPB==0: B is KxN row-major.  OPB==1: B physical NxK; opB[k,n]=B[n*ldb+k]
// Batched over blockIdx.z via element strides zsA/zsB/zsC (also used for split-K).
// 128x128 tile, 512 threads, 4x8 microtile, double-buffered LDS.
// REQUIRES: M,N multiples of 128; K multiple of 16; 16B-aligned pointers.
// ---------------------------------------------------------------------------
template<int OPA, int OPB>
__global__ void __launch_bounds__(512)
gemm_kernel(int M, int N, int K,
            const float* __restrict__ A, int lda,
            const float* __restrict__ B, int ldb,
            float* __restrict__ C, int ldc,
            float alpha,
            const float* __restrict__ Add, int ldadd, int addI,
            size_t zsA, size_t zsB, size_t zsC)
{
  constexpr int TMp = 128, TNp = 128, PAD = 4;
  A += (size_t)blockIdx.z * zsA;
  B += (size_t)blockIdx.z * zsB;
  C += (size_t)blockIdx.z * zsC;
  __shared__ float As[2][GBK][TMp + PAD];
  __shared__ float Bs[2][GBK][TNp + PAD];
  const int tid = (int)threadIdx.x;
  const int tx = tid & 15;
  const int ty = tid >> 4;
  const int bm = (int)blockIdx.y * TMp;
  const int bn = (int)blockIdx.x * TNp;

  const int arow = tid >> 2, aq = tid & 3;   // OPA==0
  const int akk = tid >> 5, amc = tid & 31;  // OPA==1
  const int bkk = tid >> 5, bnc = tid & 31;  // OPB==0
  const int brow = tid >> 2, bq = tid & 3;   // OPB==1

  float4 ra, rb;
  auto loadA = [&](int k0) {
    if (OPA == 0) ra = *reinterpret_cast<const float4*>(&A[(size_t)(bm + arow) * lda + k0 + aq * 4]);
    else          ra = *reinterpret_cast<const float4*>(&A[(size_t)(k0 + akk) * lda + bm + amc * 4]);
  };
  auto storeA = [&](int buf) {
    if (OPA == 0) {
      As[buf][aq * 4 + 0][arow] = ra.x; As[buf][aq * 4 + 1][arow] = ra.y;
      As[buf][aq * 4 + 2][arow] = ra.z; As[buf][aq * 4 + 3][arow] = ra.w;
    } else {
      *reinterpret_cast<float4*>(&As[buf][akk][amc * 4]) = ra;
    }
  };
  auto loadB = [&](int k0) {
    if (OPB == 0) rb = *reinterpret_cast<const float4*>(&B[(size_t)(k0 + bkk) * ldb + bn + bnc * 4]);
    else          rb = *reinterpret_cast<const float4*>(&B[(size_t)(bn + brow) * ldb + k0 + bq * 4]);
  };
  auto storeB = [&](int buf) {
    if (OPB == 0) {
      *reinterpret_cast<float4*>(&Bs[buf][bkk][bnc * 4]) = rb;
    } else {
      Bs[buf][bq * 4 + 0][brow] = rb.x; Bs[buf][bq * 4 + 1][brow] = rb.y;
      Bs[buf][bq * 4 + 2][brow] = rb.z; Bs[buf][bq * 4 + 3][brow] = rb.w;
    }
  };

  float acc[4][8];
#pragma unroll
  for (int i = 0; i < 4; ++i)
#pragma unroll
    for (int j = 0; j < 8; ++j) acc[i][j] = 0.f;

  const int nk = K / GBK;
  loadA(0); loadB(0); storeA(0); storeB(0);
  __syncthreads();

  for (int t = 0; t < nk; ++t) {
    const int cur = t & 1;
    if (t + 1 < nk) { loadA((t + 1) * GBK); loadB((t + 1) * GBK); }
#pragma unroll
    for (int kk = 0; kk < GBK; ++kk) {
      float a[4], b[8];
      *reinterpret_cast<float4*>(a) = *reinterpret_cast<const float4*>(&As[cur][kk][ty * 4]);
      *reinterpret_cast<float4*>(&b[0]) = *reinterpret_cast<const float4*>(&Bs[cur][kk][tx * 4]);
      *reinterpret_cast<float4*>(&b[4]) = *reinterpret_cast<const float4*>(&Bs[cur][kk][64 + tx * 4]);
#pragma unroll
      for (int i = 0; i < 4; ++i)
#pragma unroll
        for (int j = 0; j < 8; ++j)
          acc[i][j] = fmaf(a[i], b[j], acc[i][j]);
    }
    if (t + 1 < nk) { storeA(cur ^ 1); storeB(cur ^ 1); }
    __syncthreads();
  }

#pragma unroll
  for (int i = 0; i < 4; ++i) {
    const int gm = bm + ty * 4 + i;
#pragma unroll
    for (int g = 0; g < 2; ++g) {
      const int gn0 = bn + g * 64 + tx * 4;
      float vv[4];
#pragma unroll
      for (int j = 0; j < 4; ++j) vv[j] = alpha * acc[i][g * 4 + j];
      if (Add) {
        const float4 ad = *reinterpret_cast<const float4*>(&Add[(size_t)gm * ldadd + gn0]);
        vv[0] += ad.x; vv[1] += ad.y; vv[2] += ad.z; vv[3] += ad.w;
      }
      if (addI) {
#pragma unroll
        for (int j = 0; j < 4; ++j) if (gm == gn0 + j) vv[j] += 1.f;
      }
      float4 v; v.x = vv[0]; v.y = vv[1]; v.z = vv[2]; v.w = vv[3];
      *reinterpret_cast<float4*>(&C[(size_t)gm * ldc + gn0]) = v;
    }
  }
  (void)M; (void)N;
}

// sum ks partials (compact MxN each) + epilogue
__global__ __launch_bounds__(256)
void reduce_split_kernel(int N, int ldc, float* __restrict__ C,
                         const float* __restrict__ PS, long long MN, int ks,
                         float alpha, const float* __restrict__ Add, int ldadd, int addI)
{
  long long i4 = ((long long)blockIdx.x * 256 + threadIdx.x) * 4;
  if (i4 >= MN) return;
  float4 s = *reinterpret_cast<const float4*>(&PS[i4]);
  for (int z = 1; z < ks; ++z) {
    const float4 p = *reinterpret_cast<const float4*>(&PS[(size_t)z * MN + i4]);
    s.x += p.x; s.y += p.y; s.z += p.z; s.w += p.w;
  }
  const int m = (int)(i4 / N), n = (int)(i4 % N);
  float vv[4] = { alpha * s.x, alpha * s.y, alpha * s.z, alpha * s.w };
  if (Add) {
    const float4 ad = *reinterpret_cast<const float4*>(&Add[(size_t)m * ldadd + n]);
    vv[0] += ad.x; vv[1] += ad.y; vv[2] += ad.z; vv[3] += ad.w;
  }
  if (addI) {
#pragma unroll
    for (int j = 0; j < 4; ++j) if (m == n + j) vv[j] += 1.f;
  }
  float4 v; v.x = vv[0]; v.y = vv[1]; v.z = vv[2]; v.w = vv[3];
  *reinterpret_cast<float4*>(&C[(size_t)m * ldc + n]) = v;
}

template<int OPA, int OPB>
static void gemm_launch(hipStream_t st, int M, int N, int K,
                        const float* A, int lda, size_t zsA,
                        const float* B, int ldb, size_t zsB,
                        float* C, int ldc, size_t zsC,
                        float alpha, const float* Add, int ldadd, int addI, int batch)
{
  // split-K decision (batch-1 only)
  int ks = 1;
  if (batch == 1 && g_ps_ok && K >= 512) {
    long long blocks = (long long)(M / 128) * (N / 128);
    long long MN = (long long)M * N;
    while (ks < 8 && blocks * ks < 512 && (K % (32 * ks)) == 0 && (long long)(ks * 2) * MN <= g_ps_cap)
      ks *= 2;
  }
  if (ks > 1) {
    const int Kp = K / ks;
    const long long MN = (long long)M * N;
    const size_t sA = (OPA == 0) ? (size_t)Kp : (size_t)Kp * lda;
    const size_t sB = (OPB == 0) ? (size_t)Kp * ldb : (size_t)Kp;
    dim3 grid(N / 128, M / 128, ks), blk(512);
    gemm_kernel<OPA, OPB><<<grid, blk, 0, st>>>(M, N, Kp, A, lda, B, ldb,
                                                g_ps, N, 1.f, nullptr, 0, 0, sA, sB, (size_t)MN);
    reduce_split_kernel<<<(int)cdiv((int)(MN / 4), 256), 256, 0, st>>>(
        N, ldc, C, g_ps, MN, ks, alpha, Add, ldadd, addI);
  } else {
    dim3 grid(N / 128, M / 128, batch), blk(512);
    gemm_kernel<OPA, OPB><<<grid, blk, 0, st>>>(M, N, K, A, lda, B, ldb,
                                                C, ldc, alpha, Add, ldadd, addI, zsA, zsB, zsC);
  }
}

static void gemm_b(hipStream_t st, int opa, int opb, int M, int N, int K,
                   const float* A, int lda, size_t zsA,
                   const float* B, int ldb, size_t zsB,
                   float* C, int ldc, size_t zsC,
                   float alpha, const float* Add, int ldadd, int addI, int batch)
{
  if (opa == 0 && opb == 0)
    gemm_launch<0,0>(st, M, N, K, A, lda, zsA, B, ldb, zsB, C, ldc, zsC, alpha, Add, ldadd, addI, batch);
  else if (opa == 0 && opb == 1)
    gemm_launch<0,1>(st, M, N, K, A, lda, zsA, B, ldb, zsB, C, ldc, zsC, alpha, Add, ldadd, addI, batch);
  else
    gemm_launch<1,0>(st, M, N, K, A, lda, zsA, B, ldb, zsB, C, ldc, zsC, alpha, Add, ldadd, addI, batch);
}

static void gemm(hipStream_t st, int opa, int opb, int M, int N, int K,
                 const float* A, int lda, const float* B, int ldb,
                 float* C, int ldc, float alpha,
                 const float* Add, int ldadd, int addI)
{
  gemm_b(st, opa, opb, M, N, K, A, lda, 0, B, ldb, 0, C, ldc, 0, alpha, Add, ldadd, addI, 1);
}

// ---------------------------------------------------------------------------
// Matvec helpers
// ---------------------------------------------------------------------------
__global__ __launch_bounds__(256)
void mv_n_kernel(int M, int K, const float* A, int lda, const float* x, float* y)
{
  int m = (int)blockIdx.x;
  if (m >= M) return;
  const float* row = A + (size_t)m * lda;
  float s = 0.f;
  for (int k = (int)threadIdx.x; k < K; k += 256) s += row[k] * x[k];
  __shared__ float red[256];
  red[threadIdx.x] = s;
  __syncthreads();
  for (int off = 128; off > 0; off >>= 1) {
    if ((int)threadIdx.x < off) red[threadIdx.x] += red[threadIdx.x + off];
    __syncthreads();
  }
  if (threadIdx.x == 0) y[m] = red[0];
}

__global__ __launch_bounds__(256)
void mv_t_kernel(int Nrows, int Ncols, const float* A, int lda,
                 const float* x, const float* addv, float* w)
{
  int e = (int)(blockIdx.x * blockDim.x + threadIdx.x);
  if (e >= Ncols) return;
  float s = 0.f;
  for (int n = 0; n < Nrows; ++n) s += A[(size_t)n * lda + e] * x[n];
  if (addv) s += addv[e];
  w[e] = s;
}

__global__ __launch_bounds__(256)
void mv_t3_kernel(int Nrows, int Ncols, const float* A, int lda,
                  const float* x0, const float* x1, const float* x2,
                  float* w0, float* w1, float* w2)
{
  int e = (int)(blockIdx.x * blockDim.x + threadIdx.x);
  if (e >= Ncols) return;
  float s0 = 0.f, s1 = 0.f, s2 = 0.f;
  for (int n = 0; n < Nrows; ++n) {
    float b = A[(size_t)n * lda + e];
    s0 += b * x0[n]; s1 += b * x1[n]; s2 += b * x2[n];
  }
  w0[e] = s0; w1[e] = s1; w2[e] = s2;
}

// ---------------------------------------------------------------------------
// elementwise helpers
// ---------------------------------------------------------------------------
__global__ __launch_bounds__(256)
void scale_cols_kernel(long long total, int E, const float* B, const float* sv, float* out)
{
  long long i = (long long)blockIdx.x * blockDim.x + threadIdx.x;
  if (i < total) {
    int e = (int)(i % E);
    out[i] = B[i] * sv[e];
  }
}

__global__ __launch_bounds__(256)
void build_h_kernel(long long total, int E,
                    const float* B, const float* LB, const float* L2B,
                    const float* w0, const float* w1, const float* w2,
                    const float* a, float* H)
{
  long long i = (long long)blockIdx.x * blockDim.x + threadIdx.x;
  if (i < total) {
    int e = (int)(i % E);
    float a1 = a[1], a2 = a[2], a3 = a[3];
    float b = B[i], lb = LB[i], l2b = L2B[i];
    H[i] = w0[e] * (a1 * b + a2 * lb + a3 * l2b)
         + w1[e] * (a2 * b + a3 * lb)
         + w2[e] * (a3 * b);
  }
}

__global__ __launch_bounds__(256)
void poly_resid_kernel(int Nn, const float* a, const float* q,
                       const float* c1, const float* c2, const float* c3,
                       const float* y, float* resid)
{
  int n = (int)(blockIdx.x * blockDim.x + threadIdx.x);
  if (n < Nn)
    resid[n] = y[n] - (a[0] * q[n] + a[1] * c1[n] + a[2] * c2[n] + a[3] * c3[n]);
}

__global__ __launch_bounds__(256)
void fzero_kernel(float* p, long long n)
{
  long long i = (long long)blockIdx.x * blockDim.x + threadIdx.x;
  if (i < n) p[i] = 0.f;
}

// ---------------------------------------------------------------------------
// index handling
// ---------------------------------------------------------------------------
__global__ __launch_bounds__(256)
void conv_idx_kernel(const void* src, int n, int* dst)
{
  const unsigned* u = (const unsigned*)src;
  bool is64 = (u[1] | u[3] | u[5] | u[7]) == 0u;
  int i = (int)(blockIdx.x * blockDim.x + threadIdx.x);
  if (i < n) dst[i] = is64 ? (int)((const long long*)src)[i] : ((const int*)src)[i];
}

__global__ __launch_bounds__(256)
void fill_int_kernel(int* p, int n, int v)
{
  int i = (int)(blockIdx.x * blockDim.x + threadIdx.x);
  if (i < n) p[i] = v;
}

__global__ __launch_bounds__(256)
void scatter_inv_kernel(const int* conn, int K, int* inv)
{
  int i = (int)(blockIdx.x * blockDim.x + threadIdx.x);
  if (i < K) inv[conn[i]] = i;
}

__global__ __launch_bounds__(256)
void mask_s_kernel(int E, const float* s_upd, const int* inv, float* s2, float* outS)
{
  int e = (int)(blockIdx.x * blockDim.x + threadIdx.x);
  if (e < E) {
    float v = (inv[e] >= 0) ? s_upd[e] : 0.f;
    s2[e] = v;
    outS[e] = v;
  }
}

__global__ __launch_bounds__(256)
void gather_cols_kernel(int Nr, int Kc, int E, const float* src, const int* conn, float* dst)
{
  long long i = (long long)blockIdx.x * blockDim.x + threadIdx.x;
  if (i < (long long)Nr * Kc) {
    int n = (int)(i / Kc), c = (int)(i % Kc);
    dst[i] = src[(size_t)n * E + conn[c]];
  }
}

__global__ __launch_bounds__(256)
void gather_scc_kernel(int Kc, int E, const float* Sig, const int* conn, float* Scc)
{
  long long i = (long long)blockIdx.x * blockDim.x + threadIdx.x;
  if (i < (long long)Kc * Kc) {
    int r = (int)(i / Kc), c = (int)(i % Kc);
    Scc[i] = Sig[(size_t)conn[r] * E + conn[c]];
  }
}

__global__ __launch_bounds__(256)
void write_sigma_out_kernel(long long total, int E, const float* Small, int Kc,
                            const int* inv, float* out)
{
  long long i = (long long)blockIdx.x * blockDim.x + threadIdx.x;
  if (i < total) {
    int r = (int)(i / E), c = (int)(i % E);
    int ir = inv[r], ic = inv[c];
    out[i] = (ir >= 0 && ic >= 0) ? Small[(size_t)ir * Kc + ic] : 0.f;
  }
}

// ---------------------------------------------------------------------------
// Fused Cholesky leaf: factor 128x128 diag block (lower, rank-4 right-looking)
// AND compute invL of that block (column-owner threads, no barriers).
// Writes ONLY invL (to Linv at (off,off)).
// ---------------------------------------------------------------------------
__global__ __launch_bounds__(256)
void chol_leaf_kernel(const float* __restrict__ S, int lda, int off,
                      float* __restrict__ Linv, int ldi)
{
  __shared__ float T[128][132];
  __shared__ float X[128][128];
  const int tid = (int)threadIdx.x;
  const float* Ab = S + (size_t)off * lda + off;
  for (int idx = tid; idx < 128 * 32; idx += 256) {
    int r = idx >> 5, c4 = (idx & 31) << 2;
    const float4 v = *reinterpret_cast<const float4*>(&Ab[(size_t)r * lda + c4]);
    *reinterpret_cast<float4*>(&T[r][c4]) = v;
    X[r][c4 + 0] = (r == c4 + 0) ? 1.f : 0.f;
    X[r][c4 + 1] = (r == c4 + 1) ? 1.f : 0.f;
    X[r][c4 + 2] = (r == c4 + 2) ? 1.f : 0.f;
    X[r][c4 + 3] = (r == c4 + 3) ? 1.f : 0.f;
  }
  __syncthreads();
  const int g = tid >> 5, lane = tid & 31;
  for (int j0 = 0; j0 < 128; j0 += 4) {
    for (int t = 0; t < 4; ++t) {
      int j = j0 + t;
      if (tid < 128 && tid >= j) {
        float s = T[tid][j];
        for (int u = 0; u < t; ++u) s -= T[tid][j0 + u] * T[j][j0 + u];
        T[tid][j] = s;
      }
      __syncthreads();
      float d = sqrtf(T[j][j]);
      if (tid < 128 && tid >= j) T[tid][j] = (tid == j) ? d : T[tid][j] / d;
      __syncthreads();
    }
    for (int r = j0 + 4 + g; r < 128; r += 8) {
      const float4 lr = *reinterpret_cast<const float4*>(&T[r][j0]);
      for (int c = j0 + 4 + lane; c <= r; c += 32) {
        const float4 lc = *reinterpret_cast<const float4*>(&T[c][j0]);
        T[r][c] -= lr.x * lc.x + lr.y * lc.y + lr.z * lc.z + lr.w * lc.w;
      }
    }
    __syncthreads();
  }
  if (tid < 128) {
    const int c = tid;
    for (int j0 = 0; j0 < 128; j0 += 4) {
      float s, xp0, xp1, xp2, xp3;
      s = X[j0 + 0][c];
      xp0 = s / T[j0 + 0][j0 + 0]; X[j0 + 0][c] = xp0;
      s = X[j0 + 1][c] - T[j0 + 1][j0] * xp0;
      xp1 = s / T[j0 + 1][j0 + 1]; X[j0 + 1][c] = xp1;
      s = X[j0 + 2][c] - T[j0 + 2][j0] * xp0 - T[j0 + 2][j0 + 1] * xp1;
      xp2 = s / T[j0 + 2][j0 + 2]; X[j0 + 2][c] = xp2;
      s = X[j0 + 3][c] - T[j0 + 3][j0] * xp0 - T[j0 + 3][j0 + 1] * xp1 - T[j0 + 3][j0 + 2] * xp2;
      xp3 = s / T[j0 + 3][j0 + 3]; X[j0 + 3][c] = xp3;
      for (int i = j0 + 4; i < 128; ++i) {
        const float4 lr = *reinterpret_cast<const float4*>(&T[i][j0]);
        X[i][c] -= lr.x * xp0 + lr.y * xp1 + lr.z * xp2 + lr.w * xp3;
      }
    }
  }
  __syncthreads();
  float* Ob = Linv + (size_t)off * ldi + off;
  for (int idx = tid; idx < 128 * 32; idx += 256) {
    int r = idx >> 5, c4 = (idx & 31) << 2;
    float4 v;
    v.x = X[r][c4]; v.y = X[r][c4 + 1]; v.z = X[r][c4 + 2]; v.w = X[r][c4 + 3];
    *reinterpret_cast<float4*>(&Ob[(size_t)r * ldi + c4]) = v;
  }
}

// ---------------------------------------------------------------------------
// SPD inverse: S (n x n) -> Sinv. S is destroyed (holds factor panels).
// ---------------------------------------------------------------------------
static void spd_inverse(hipStream_t st, float* S, float* Linv, float* Sinv, float* TT, int n)
{
  long long nn = (long long)n * n;
  fzero_kernel<<<cdiv((int)nn, 256), 256, 0, st>>>(Linv, nn);
  for (int off = 0; off < n; off += 128) {
    chol_leaf_kernel<<<1, 256, 0, st>>>(S, n, off, Linv, n);
    int mrem = n - off - 128;
    if (mrem > 0) {
      float* P = S + (size_t)(off + 128) * n + off;
      gemm(st, 0, 1, mrem, 128, 128, P, n, Linv + (size_t)off * (n + 1), n, P, n, 1.f, nullptr, 0, 0);
      float* Ct = S + (size_t)(off + 128) * (n + 1);
      gemm(st, 0, 1, mrem, mrem, 128, P, n, P, n, Ct, n, -1.f, Ct, n, 0);
    }
  }
  for (int m = 128; m < n; m <<= 1) {
    int pairs = n / (2 * m);
    size_t zs = (size_t)2 * m * (n + 1);
    gemm_b(st, 0, 0, m, m, m, S + (size_t)m * n, n, zs, Linv, n, zs,
           TT, m, (size_t)m * m, 1.f, nullptr, 0, 0, pairs);
    gemm_b(st, 0, 0, m, m, m, Linv + (size_t)m * (n + 1), n, zs, TT, m, (size_t)m * m,
           Linv + (size_t)m * n, n, zs, -1.f, nullptr, 0, 0, pairs);
  }
  gemm(st, 1, 0, n, n, n, Linv, n, Linv, n, Sinv, n, 1.f, nullptr, 0, 0);
}

// ---------------------------------------------------------------------------
extern "C" void kernel_launch(void* const* d_in, const int* in_sizes, int n_in,
                              void* d_out, int out_size, void* d_ws, size_t ws_size,
                              hipStream_t stream)
{
  const float* F  = (const float*)d_in[0];
  const float* B  = (const float*)d_in[1];
  const float* V  = (const float*)d_in[2];
  const float* W  = (const float*)d_in[3];
  const float* Sg = (const float*)d_in[4];
  const float* sv = (const float*)d_in[5];
  const float* av = (const float*)d_in[6];
  const float* q  = (const float*)d_in[7];
  const float* y  = (const float*)d_in[8];
  const void*  connRaw = d_in[10];

  const int E  = in_sizes[5];
  const int Nn = in_sizes[7];
  const int Kc = in_sizes[10];

  const size_t EE = (size_t)E * E;
  const size_t NE = (size_t)Nn * E;
  const size_t NN = (size_t)Nn * Nn;
  const size_t NK = (size_t)Nn * Kc;
  const size_t KK = (size_t)Kc * Kc;

  float* ws = (float*)d_ws;
  float* EE_A = ws;
  float* EE_B = EE_A + EE;
  float* NE_1 = EE_B + EE;
  float* NE_2 = NE_1 + NE;   // Y / TT / U / T10 (time-disjoint)
  float* NE_3 = NE_2 + NE;
  float* NN_1 = NE_3 + NE;   // L / S factor
  float* NN_2 = NN_1 + NN;   // Linv
  float* NN_3 = NN_2 + NN;   // Sinv
  float* vec  = NN_3 + NN;
  float* s1    = vec;            vec += E;
  float* c1    = vec;            vec += Nn;
  float* c2    = vec;            vec += Nn;
  float* c3    = vec;            vec += Nn;
  float* w0    = vec;            vec += E;
  float* w1    = vec;            vec += E;
  float* w2    = vec;            vec += E;
  float* resid = vec;            vec += Nn;
  float* s_upd = vec;            vec += E;
  float* s2    = vec;            vec += E;
  int* conn32  = (int*)vec;
  int* invc    = conn32 + Kc;
  float* after_ints = (float*)(invc + E);

  // split-K partial workspace (2*EE floats), gated on ws_size
  uintptr_t psa = ((uintptr_t)after_ints + 255) & ~(uintptr_t)255;
  g_ps = (float*)psa;
  g_ps_cap = (long long)2 * (long long)EE;
  size_t need = (size_t)((char*)(g_ps + g_ps_cap) - (char*)d_ws);
  g_ps_ok = (need <= ws_size) ? 1 : 0;

  float* outS   = (float*)d_out;   // E
  float* outSig = outS + E;        // E*E; scratch until final write
  float* EE_C   = outSig;
  float* TT     = NE_2;            // bisection temp (dead region at that time)

  const long long totNE = (long long)Nn * E;
  const long long totEE = (long long)E * E;

  // ---- stage 1 ----
  mv_n_kernel<<<E, 256, 0, stream>>>(E, E, F, E, sv, s1);                        // s1 = F s
  gemm(stream, 0, 0, E, E, E, F, E, Sg, E, EE_A, E, 1.f, nullptr, 0, 0);         // G1 = F Sigma
  gemm(stream, 0, 1, E, E, E, EE_A, E, F, E, EE_B, E, 1.f, V, E, 0);             // Sigma1 = G1 F^T + V
  scale_cols_kernel<<<cdiv((int)totNE, 256), 256, 0, stream>>>(totNE, E, B, s1, NE_1); // Bs
  gemm(stream, 0, 1, Nn, Nn, E, NE_1, E, B, E, NN_1, Nn, 1.f, nullptr, 0, 0);    // L = Bs B^T
  mv_n_kernel<<<Nn, 256, 0, stream>>>(Nn, Nn, NN_1, Nn, q, c1);
  mv_n_kernel<<<Nn, 256, 0, stream>>>(Nn, Nn, NN_1, Nn, c1, c2);
  mv_n_kernel<<<Nn, 256, 0, stream>>>(Nn, Nn, NN_1, Nn, c2, c3);
  mv_t3_kernel<<<cdiv(E, 256), 256, 0, stream>>>(Nn, E, B, E, q, c1, c2, w0, w1, w2);
  poly_resid_kernel<<<cdiv(Nn, 256), 256, 0, stream>>>(Nn, av, q, c1, c2, c3, y, resid);
  gemm(stream, 0, 0, Nn, E, Nn, NN_1, Nn, B, E, NE_1, E, 1.f, nullptr, 0, 0);    // LB
  gemm(stream, 0, 0, Nn, E, Nn, NN_1, Nn, NE_1, E, NE_2, E, 1.f, nullptr, 0, 0); // L2B
  build_h_kernel<<<cdiv((int)totNE, 256), 256, 0, stream>>>(totNE, E, B, NE_1, NE_2, w0, w1, w2, av, NE_3); // H
  gemm(stream, 0, 0, Nn, E, E, NE_3, E, EE_B, E, NE_1, E, 1.f, nullptr, 0, 0);   // T2 = H Sigma1
  gemm(stream, 0, 1, Nn, Nn, E, NE_1, E, NE_3, E, NN_1, Nn, 1.f, W, Nn, 0);      // S = T2 H^T + W
  spd_inverse(stream, NN_1, NN_2, NN_3, TT, Nn);                                 // Sinv in NN_3
  gemm(stream, 0, 0, Nn, E, Nn, NN_3, Nn, NE_1, E, NE_2, E, 1.f, nullptr, 0, 0); // Y = Sinv T2
  mv_t_kernel<<<cdiv(E, 256), 256, 0, stream>>>(Nn, E, NE_2, E, resid, s1, s_upd); // s_upd = s1 + Y^T resid
  // Joseph form without forming ImKH (K = Y^T):
  gemm(stream, 1, 0, E, E, Nn, NE_2, E, NE_1, E, EE_A, E, -1.f, EE_B, E, 0);     // T3 = Sigma1 - Y^T T2
  gemm(stream, 0, 1, E, Nn, E, EE_A, E, NE_3, E, NE_1, Nn, 1.f, nullptr, 0, 0);  // U = T3 H^T
  gemm(stream, 0, 0, E, E, Nn, NE_1, Nn, NE_2, E, EE_C, E, -1.f, EE_A, E, 0);    // T4 = T3 - U Y
  gemm(stream, 1, 0, E, Nn, Nn, NE_2, E, W, Nn, NE_1, Nn, 1.f, nullptr, 0, 0);   // T5 = Y^T W
  gemm(stream, 0, 0, E, E, Nn, NE_1, Nn, NE_2, E, EE_B, E, 1.f, EE_C, E, 0);     // Sigma2 = T5 Y + T4

  // ---- masking / stage 2 ----
  conv_idx_kernel<<<cdiv(Kc, 256), 256, 0, stream>>>(connRaw, Kc, conn32);
  fill_int_kernel<<<cdiv(E, 256), 256, 0, stream>>>(invc, E, -1);
  scatter_inv_kernel<<<cdiv(Kc, 256), 256, 0, stream>>>(conn32, Kc, invc);
  mask_s_kernel<<<cdiv(E, 256), 256, 0, stream>>>(E, s_upd, invc, s2, outS);

  scale_cols_kernel<<<cdiv((int)totNE, 256), 256, 0, stream>>>(totNE, E, B, s2, NE_1); // Bs2
  gemm(stream, 0, 1, Nn, Nn, E, NE_1, E, B, E, NN_1, Nn, 1.f, nullptr, 0, 0);    // L2
  mv_n_kernel<<<Nn, 256, 0, stream>>>(Nn, Nn, NN_1, Nn, q, c1);
  mv_n_kernel<<<Nn, 256, 0, stream>>>(Nn, Nn, NN_1, Nn, c1, c2);
  mv_t3_kernel<<<cdiv(E, 256), 256, 0, stream>>>(Nn, E, B, E, q, c1, c2, w0, w1, w2);
  gemm(stream, 0, 0, Nn, E, Nn, NN_1, Nn, B, E, NE_1, E, 1.f, nullptr, 0, 0);    // L2 B
  gemm(stream, 0, 0, Nn, E, Nn, NN_1, Nn, NE_1, E, NE_2, E, 1.f, nullptr, 0, 0); // L2^2 B
  build_h_kernel<<<cdiv((int)totNE, 256), 256, 0, stream>>>(totNE, E, B, NE_1, NE_2, w0, w1, w2, av, NE_3); // H2full
  gather_cols_kernel<<<cdiv((int)NK, 256), 256, 0, stream>>>(Nn, Kc, E, NE_3, conn32, EE_A);        // H2 (Nn x Kc)
  gather_scc_kernel<<<cdiv((int)KK, 256), 256, 0, stream>>>(Kc, E, EE_B, conn32, EE_A + NK);        // Scc (Kc x Kc)
  gemm(stream, 0, 0, Nn, Kc, Kc, EE_A, Kc, EE_A + NK, Kc, EE_B, Kc, 1.f, nullptr, 0, 0); // T7 = H2 Scc
  gemm(stream, 0, 1, Nn, Nn, Kc, EE_B, Kc, EE_A, Kc, NN_1, Nn, 1.f, W, Nn, 0);   // S2 = T7 H2^T + W
  spd_inverse(stream, NN_1, NN_2, NN_3, TT, Nn);                                 // Sinv2 in NN_3
  gemm(stream, 0, 0, Nn, Kc, Nn, NN_3, Nn, EE_B, Kc, NE_1, Kc, 1.f, nullptr, 0, 0);  // Y2 = Sinv2 T7
  gemm(stream, 1, 0, Kc, Kc, Nn, NE_1, Kc, EE_A, Kc, EE_C, Kc, -1.f, nullptr, 0, 1); // ImKH2 = I - Y2^T H2
  gemm(stream, 0, 0, Kc, Kc, Kc, EE_C, Kc, EE_A + NK, Kc, EE_C + KK, Kc, 1.f, nullptr, 0, 0); // T8 = ImKH2 Scc
  gemm(stream, 0, 1, Kc, Kc, Kc, EE_C + KK, Kc, EE_C, Kc, EE_A + NK, Kc, 1.f, nullptr, 0, 0); // T9 = T8 ImKH2^T
  gemm(stream, 1, 0, Kc, Nn, Nn, NE_1, Kc, W, Nn, NE_2, Nn, 1.f, nullptr, 0, 0); // T10 = Y2^T W
  gemm(stream, 0, 0, Kc, Kc, Nn, NE_2, Nn, NE_1, Kc, EE_A + NK, Kc, 1.f, EE_A + NK, Kc, 0); // Small = T10 Y2 + T9

  write_sigma_out_kernel<<<cdiv((int)totEE, 256), 256, 0, stream>>>(totEE, E, EE_A + NK, Kc, invc, outSig);

  (void)n_in; (void)out_size; (void)ws_size;
}